// Round 8
// baseline (235.105 us; speedup 1.0000x reference)
//
#include <hip/hip_runtime.h>
#include <hip/hip_bf16.h>

typedef _Float16 f16_t;
typedef unsigned short u16;
typedef unsigned int u32;
typedef float f32x4 __attribute__((ext_vector_type(4)));
typedef f16_t f16x8 __attribute__((ext_vector_type(8)));
typedef u16 u16x8 __attribute__((ext_vector_type(8)));
typedef u16 u16x4 __attribute__((ext_vector_type(4)));

#define MROWS 4096
#define NHEADS 4
#define COUT 64
#define OHF 256   // NHEADS*COUT
#define NCLS 40
#define LOG2E 1.4426950408889634f
#define PLD 264   // partial row length (u16): 256 acc + 4 rowsum + pad

static __device__ __forceinline__ u16 f16b(float x) {
    return __builtin_bit_cast(u16, (f16_t)x);
}
static __device__ __forceinline__ float f16f(u16 x) {
    return (float)__builtin_bit_cast(f16_t, x);
}

// ---------------- init: A->AbitsT (transposed bitmask) + prep (Cw, va1, va2, dmu) ----------------
// blocks 0..511: bits (8 rows each, LDS-staged transposed writes)
// blocks 512..771: prep
__global__ __launch_bounds__(256) void init_kernel(const int* __restrict__ A,
                                                   u32* __restrict__ AbitsT,
                                                   const float* __restrict__ W1w,
                                                   const float* __restrict__ W1b,
                                                   const float* __restrict__ a1,
                                                   const float* __restrict__ W2w,
                                                   const float* __restrict__ W2b,
                                                   const float* __restrict__ W3w,
                                                   const float* __restrict__ W3b,
                                                   const float* __restrict__ a2,
                                                   float* __restrict__ Cwf,
                                                   float* __restrict__ cbf,
                                                   float* __restrict__ va1,
                                                   float* __restrict__ vc1,
                                                   float* __restrict__ va2,
                                                   float* __restrict__ vc2,
                                                   u32* __restrict__ dmu) {
    __shared__ u32 W[8][128];
    __shared__ float u[8][64];
    const int bx = blockIdx.x, tid = threadIdx.x;
    if (bx < 512) {
        const int i0 = bx * 8;
        const int lane = tid & 63, wv = tid >> 6;
        // 8 rows x 64 j-blocks = 512 ballot tasks, 4 waves
        for (int task = wv; task < 512; task += 4) {
            const int r = task >> 6, jb = task & 63;
            int aval = A[(size_t)(i0 + r) * MROWS + jb * 64 + lane];
            unsigned long long bal = __ballot(aval != 0);
            if (lane == 0)      W[r][jb * 2]     = (u32)bal;
            else if (lane == 1) W[r][jb * 2 + 1] = (u32)(bal >> 32);
        }
        __syncthreads();
        // transposed coalesced-ish writes: AbitsT[jw*4096 + i0 + r]
        for (int idx = tid; idx < 1024; idx += 256) {
            const int jw = idx >> 3, r = idx & 7;
            AbitsT[(size_t)jw * MROWS + i0 + r] = W[r][jw];
        }
        return;
    }
    const int bid = bx - 512;
    if (bid < 256) {
        float acc = 0.f;
        for (int t = 0; t < 64; ++t)
            acc += W2w[bid * 64 + t] * W3w[t * 256 + tid];
        Cwf[bid * 256 + tid] = acc;
        if (tid == 0) {
            float b = 0.f;
            for (int t = 0; t < 64; ++t) b += W2w[bid * 64 + t] * W3b[t];
            cbf[bid] = b + W2b[bid];
        }
    } else if (bid < 258) {
        const int k = (bid - 256) * 256 + tid;
#pragma unroll
        for (int hs = 0; hs < 8; ++hs) {
            const int h = hs >> 1, s = hs & 1;
            float acc = 0.f;
            for (int c = 0; c < COUT; ++c)
                acc += W1w[(size_t)(h * COUT + c) * 512 + k] * a1[h * 128 + s * COUT + c];
            va1[hs * 512 + k] = acc;
        }
        if (bid == 256 && tid == 0) {
            for (int hs = 0; hs < 8; ++hs) {
                const int h = hs >> 1, s = hs & 1;
                float b = 0.f;
                for (int c = 0; c < COUT; ++c) b += W1b[h * COUT + c] * a1[h * 128 + s * COUT + c];
                vc1[hs] = b;
            }
        }
    } else if (bid == 258) {
#pragma unroll
        for (int e = tid * 2; e < tid * 2 + 2; ++e) {
            const int hs = e >> 6, t = e & 63;
            const int h = hs >> 1, s = hs & 1;
            float acc = 0.f;
            for (int c = 0; c < COUT; ++c)
                acc += W2w[(size_t)(h * COUT + c) * 64 + t] * a2[h * 128 + s * COUT + c];
            u[hs][t] = acc;
        }
        __syncthreads();
#pragma unroll
        for (int hs = 0; hs < 8; ++hs) {
            float acc = 0.f;
            for (int t = 0; t < 64; ++t) acc += u[hs][t] * W3w[t * 256 + tid];
            va2[hs * 256 + tid] = acc;
        }
        if (tid == 0) {
            for (int hs = 0; hs < 8; ++hs) {
                const int h = hs >> 1, s = hs & 1;
                float b = 0.f;
                for (int t = 0; t < 64; ++t) b += u[hs][t] * W3b[t];
                for (int c = 0; c < COUT; ++c) b += W2b[h * COUT + c] * a2[h * 128 + s * COUT + c];
                vc2[hs] = b;
            }
        }
    } else {
        if (tid < 8) dmu[tid] = 0u;   // monotone-mapped -inf
    }
}

// ---------------- GEMM: WhT[n][m] = f16( sum_k A[m,k]*B[n,k] + bias[n] ) ----------------
__global__ __launch_bounds__(256) void gemm16(const float* __restrict__ A,
                                              const float* __restrict__ B,
                                              const float* __restrict__ bias,
                                              u16* __restrict__ WhT, int K) {
    __shared__ u16 Al[64][40];
    __shared__ u16 Bl[64][40];
    const int tid = threadIdx.x;
    const int lane = tid & 63, wv = tid >> 6;
    const int l15 = lane & 15, g = lane >> 4;
    const int m0 = blockIdx.x * 64, n0 = blockIdx.y * 64;
    const int r = tid >> 2, c8 = (tid & 3) * 8;

    f32x4 acc[4] = {};
    for (int k0 = 0; k0 < K; k0 += 32) {
        const float4 a0 = *(const float4*)&A[(size_t)(m0 + r) * K + k0 + c8];
        const float4 a1 = *(const float4*)&A[(size_t)(m0 + r) * K + k0 + c8 + 4];
        const float4 b0 = *(const float4*)&B[(size_t)(n0 + r) * K + k0 + c8];
        const float4 b1 = *(const float4*)&B[(size_t)(n0 + r) * K + k0 + c8 + 4];
        u16x8 av, bv;
        av[0] = f16b(a0.x); av[1] = f16b(a0.y); av[2] = f16b(a0.z); av[3] = f16b(a0.w);
        av[4] = f16b(a1.x); av[5] = f16b(a1.y); av[6] = f16b(a1.z); av[7] = f16b(a1.w);
        bv[0] = f16b(b0.x); bv[1] = f16b(b0.y); bv[2] = f16b(b0.z); bv[3] = f16b(b0.w);
        bv[4] = f16b(b1.x); bv[5] = f16b(b1.y); bv[6] = f16b(b1.z); bv[7] = f16b(b1.w);
        __syncthreads();
        *(u16x8*)&Al[r][c8] = av;
        *(u16x8*)&Bl[r][c8] = bv;
        __syncthreads();
        f16x8 afr = *(const f16x8*)&Al[16 * wv + l15][8 * g];
#pragma unroll
        for (int ni = 0; ni < 4; ++ni) {
            f16x8 bfr = *(const f16x8*)&Bl[16 * ni + l15][8 * g];
            acc[ni] = __builtin_amdgcn_mfma_f32_16x16x32_f16(afr, bfr, acc[ni], 0, 0, 0);
        }
    }
#pragma unroll
    for (int ni = 0; ni < 4; ++ni) {
        const int n = n0 + 16 * ni + l15;
        const float bvs = bias[n];
        u16x4 pv;
#pragma unroll
        for (int rr = 0; rr < 4; ++rr) pv[rr] = f16b(acc[ni][rr] + bvs);
        *(u16x4*)&WhT[(size_t)n * MROWS + m0 + 16 * wv + 4 * g] = pv;
    }
}

// ---------------- scores: k-sliced, fused per-head dst max (atomicMax) ----------------
__global__ __launch_bounds__(256) void srcdst_kernel(const float* __restrict__ X, int K,
                                                     const float* __restrict__ va,
                                                     const float* __restrict__ vc,
                                                     float* __restrict__ srcT,
                                                     float* __restrict__ dstT,
                                                     u32* __restrict__ dmu) {
    __shared__ float red[32][8][8];   // [row][ki][hs]
    __shared__ float dred[4][32];
    const int tid = threadIdx.x;
    const int ii = tid >> 3, ki = tid & 7;
    const int i = blockIdx.x * 32 + ii;
    const int KS = K >> 3;
    const int k0 = ki * KS;
    float acc[8] = {};
    for (int k = k0; k < k0 + KS; k += 4) {
        const float4 xv = *(const float4*)&X[(size_t)i * K + k];
#pragma unroll
        for (int hs = 0; hs < 8; ++hs) {
            const float4 vv = *(const float4*)&va[(size_t)hs * K + k];
            acc[hs] += xv.x * vv.x + xv.y * vv.y + xv.z * vv.z + xv.w * vv.w;
        }
    }
#pragma unroll
    for (int hs = 0; hs < 8; ++hs) red[ii][ki][hs] = acc[hs];
    __syncthreads();
    {
        const int row = tid >> 3, hs = tid & 7, h = hs >> 1;
        float sum = 0.f;
#pragma unroll
        for (int kk = 0; kk < 8; ++kk) sum += red[row][kk][hs];
        const float val = sum + vc[hs];
        const int ig = blockIdx.x * 32 + row;
        if ((hs & 1) == 0) {
            srcT[h * MROWS + ig] = val;
        } else {
            dstT[h * MROWS + ig] = val;
            dred[h][row] = val;
        }
    }
    __syncthreads();
    if (tid < 4) {
        float m = -3.4e38f;
#pragma unroll
        for (int r = 0; r < 32; ++r) m = fmaxf(m, dred[tid][r]);
        const u32 b = __builtin_bit_cast(u32, m);
        const u32 key = (b & 0x80000000u) ? ~b : (b | 0x80000000u);
        atomicMax(dmu + tid, key);
    }
}

// ---------------- attention (f16 MFMA, factorized exp, ones-MFMA rowsum) ----------------
// grid (64, nchunk), 512 thr (8 waves: wave = (h, row-half)). 64 i-rows per block.
// w' = mask ? (t>=0 ? F1_i*G1_j : F2_i*G2_j) : 0, shifted so w' <= 1.
template <int JT>
__global__ __launch_bounds__(512) void attn_kernel(const u16* __restrict__ WhT,
                                                   const float* __restrict__ srcT,
                                                   const float* __restrict__ dstT,
                                                   const u32* __restrict__ AbitsT,
                                                   const u32* __restrict__ dmu,
                                                   u16* __restrict__ partial,
                                                   float* __restrict__ outF) {
    __shared__ __align__(16) unsigned char whL[256 * 128];   // 32 KB swizzled [c][j]
    const int tid = threadIdx.x;
    const int lane = tid & 63, w = tid >> 6;
    const int h = w & 3, half = w >> 2;
    const int l15 = lane & 15, g = lane >> 4;
    const int i0 = blockIdx.x * 64;
    const int chunk = blockIdx.y;
    const int xorm = (l15 & 7) << 4;          // read-side swizzle

    const u32 ku = dmu[h];
    const u32 fb = (ku & 0x80000000u) ? (ku ^ 0x80000000u) : ~ku;
    const float dmh = __builtin_bit_cast(float, fb);

    float negs_[2], F1_[2], F2_[2];
    f32x4 acc[2][4] = {};
    f32x4 acc1[2] = {};
    f16x8 ones;
#pragma unroll
    for (int e = 0; e < 8; ++e) ones[e] = (f16_t)1.0f;
#pragma unroll
    for (int mi = 0; mi < 2; ++mi) {
        const float s = srcT[h * MROWS + i0 + 32 * half + 16 * mi + l15];
        const float sd = s + dmh;
        const float C = fmaxf(sd, 0.01f * sd);
        negs_[mi] = -s;
        F1_[mi] = __builtin_amdgcn_exp2f((sd - C) * LOG2E);          // exp(s+dmh-C)
        F2_[mi] = __builtin_amdgcn_exp2f((0.01f * sd - C) * LOG2E);  // exp(.01(s+dmh)-C)
    }

    for (int jt = 0; jt < JT; ++jt) {
        const int j0 = (chunk * JT + jt) * 64;
        // ---- stage Wh tile: 256 c x 64 j, coalesced 16B chunks, swizzled LDS ----
        __syncthreads();
#pragma unroll
        for (int q = 0; q < 4; ++q) {
            const int eid = tid + 512 * q;
            const int c = eid >> 3, jo8 = eid & 7;
            u16x8 v = *(const u16x8*)&WhT[(size_t)c * MROWS + j0 + jo8 * 8];
            *(u16x8*)(whL + c * 128 + ((jo8 * 16) ^ ((c & 7) << 4))) = v;
        }
        __syncthreads();
        f16x8 af[2];
#pragma unroll
        for (int kj = 0; kj < 2; ++kj) {
            const int jk = j0 + 32 * kj + 8 * g;
            const float4 d0 = *(const float4*)&dstT[h * MROWS + jk];
            const float4 d1 = *(const float4*)&dstT[h * MROWS + jk + 4];
            float dv[8] = {d0.x, d0.y, d0.z, d0.w, d1.x, d1.y, d1.z, d1.w};
            // shared G factors (per-j, shared across both mi halves)
            float G1[8], G2[8];
#pragma unroll
            for (int e = 0; e < 8; ++e) {
                const float uu = dv[e] - dmh;
                G1[e] = __builtin_amdgcn_exp2f(uu * LOG2E);           // exp(d-dmh)
                G2[e] = __builtin_amdgcn_exp2f(uu * (0.01f * LOG2E)); // exp(.01(d-dmh))
            }
#pragma unroll
            for (int mi = 0; mi < 2; ++mi) {
                const int irow = i0 + 32 * half + 16 * mi + l15;
                const u32 word = AbitsT[(size_t)((j0 >> 5) + kj) * MROWS + irow];
                const u32 bits = (word >> (8 * g)) & 0xffu;
                f16x8 a;
#pragma unroll
                for (int e = 0; e < 8; ++e) {
                    const bool pos = dv[e] >= negs_[mi];
                    float wv = (pos ? G1[e] : G2[e]) * (pos ? F1_[mi] : F2_[mi]);
                    wv = ((bits >> e) & 1u) ? wv : 0.f;
                    a[e] = (f16_t)wv;
                }
                af[mi] = a;
            }
            // ---- MFMAs: B-fragments from swizzled LDS + ones-column rowsum ----
#pragma unroll
            for (int ni = 0; ni < 4; ++ni) {
                const int c = h * COUT + 16 * ni + l15;
                f16x8 b = *(const f16x8*)(whL + c * 128 + ((64 * kj + 16 * g) ^ xorm));
                acc[0][ni] = __builtin_amdgcn_mfma_f32_16x16x32_f16(af[0], b, acc[0][ni], 0, 0, 0);
                acc[1][ni] = __builtin_amdgcn_mfma_f32_16x16x32_f16(af[1], b, acc[1][ni], 0, 0, 0);
            }
            acc1[0] = __builtin_amdgcn_mfma_f32_16x16x32_f16(af[0], ones, acc1[0], 0, 0, 0);
            acc1[1] = __builtin_amdgcn_mfma_f32_16x16x32_f16(af[1], ones, acc1[1], 0, 0, 0);
        }
    }

    if (partial) {
        u16* pc = partial + (size_t)chunk * MROWS * PLD;
#pragma unroll
        for (int mi = 0; mi < 2; ++mi) {
#pragma unroll
            for (int ni = 0; ni < 4; ++ni)
#pragma unroll
                for (int rr = 0; rr < 4; ++rr) {
                    const int i = i0 + 32 * half + 16 * mi + 4 * g + rr;
                    pc[(size_t)i * PLD + h * COUT + 16 * ni + l15] = f16b(acc[mi][ni][rr]);
                }
#pragma unroll
            for (int rr = 0; rr < 4; ++rr)
                if (l15 == rr)
                    pc[(size_t)(i0 + 32 * half + 16 * mi + 4 * g + rr) * PLD + 256 + h] =
                        f16b(acc1[mi][rr]);
        }
    } else {
#pragma unroll
        for (int mi = 0; mi < 2; ++mi)
#pragma unroll
            for (int rr = 0; rr < 4; ++rr) {
                const int i = i0 + 32 * half + 16 * mi + 4 * g + rr;
                const float rs = acc1[mi][rr];
#pragma unroll
                for (int ni = 0; ni < 4; ++ni)
                    outF[(size_t)i * OHF + h * COUT + 16 * ni + l15] = acc[mi][ni][rr] / rs;
            }
    }
}

// ---------------- combine chunked f16 partials: block = one row ----------------
__global__ __launch_bounds__(256) void combine_kernel(const u16* __restrict__ partial,
                                                      int nchunk,
                                                      float* __restrict__ outF) {
    const int i = blockIdx.x, c = threadIdx.x, h = c >> 6;
    float v = 0.f, rs = 0.f;
    for (int ch = 0; ch < nchunk; ++ch) {
        const u16* pc = partial + (size_t)ch * MROWS * PLD + (size_t)i * PLD;
        v += f16f(pc[c]);
        rs += f16f(pc[256 + h]);
    }
    outF[(size_t)i * OHF + c] = v / rs;
}

// ---------------- classifier head, fp32 VALU ----------------
__global__ __launch_bounds__(256) void cls_kernel(const float* __restrict__ xf,
                                                  const float* __restrict__ FLw,
                                                  const float* __restrict__ FLb,
                                                  float* __restrict__ out1) {
    const int id = blockIdx.x * 256 + threadIdx.x;
    if (id >= MROWS * NCLS) return;
    const int m = id / NCLS, k = id - m * NCLS;
    float acc = FLb[k];
    for (int c = 0; c < OHF; c += 4) {
        const float4 xv = *(const float4*)&xf[(size_t)m * OHF + c];
        const float4 wv = *(const float4*)&FLw[(size_t)k * OHF + c];
        acc += xv.x * wv.x + xv.y * wv.y + xv.z * wv.z + xv.w * wv.w;
    }
    out1[id] = acc;
}

extern "C" void kernel_launch(void* const* d_in, const int* in_sizes, int n_in,
                              void* d_out, int out_size, void* d_ws, size_t ws_size,
                              hipStream_t stream) {
    const float* hIn = (const float*)d_in[0];
    const int*   A   = (const int*)d_in[1];
    const float* W1w = (const float*)d_in[2];
    const float* W1b = (const float*)d_in[3];
    const float* a1  = (const float*)d_in[4];
    const float* W3w = (const float*)d_in[5];
    const float* W3b = (const float*)d_in[6];
    const float* W2w = (const float*)d_in[7];
    const float* W2b = (const float*)d_in[8];
    const float* a2  = (const float*)d_in[9];
    const float* FLw = (const float*)d_in[10];
    const float* FLb = (const float*)d_in[11];
    float* outX = (float*)d_out;                     // x: (4096 x 256) fp32
    float* outL = outX + (size_t)MROWS * OHF;        // logits: (4096 x 40) fp32

    char* p = (char*)d_ws;
    auto alloc = [&](size_t bytes) { char* q = p; p += (bytes + 255) & ~(size_t)255; return q; };
    u32*   AbitsT = (u32*)alloc((size_t)MROWS * 128 * 4);
    u16*   WhT1  = (u16*)alloc((size_t)OHF * MROWS * 2);
    u16*   WhT2  = (u16*)alloc((size_t)OHF * MROWS * 2);
    float* x1f   = (float*)alloc((size_t)MROWS * OHF * 4);
    float* Cwf   = (float*)alloc((size_t)256 * 256 * 4);
    float* cbf   = (float*)alloc(256 * 4);
    float* va1   = (float*)alloc((size_t)8 * 512 * 4);
    float* vc1   = (float*)alloc(8 * 4);
    float* va2   = (float*)alloc((size_t)8 * 256 * 4);
    float* vc2   = (float*)alloc(8 * 4);
    float* srcT1 = (float*)alloc((size_t)NHEADS * MROWS * 4);
    float* dstT1 = (float*)alloc((size_t)NHEADS * MROWS * 4);
    float* srcT2 = (float*)alloc((size_t)NHEADS * MROWS * 4);
    float* dstT2 = (float*)alloc((size_t)NHEADS * MROWS * 4);
    u32*   dmu   = (u32*)alloc(8 * 4);               // [0..3]=layer1, [4..7]=layer2
    size_t fixed = (size_t)(p - (char*)d_ws);
    int nchunk = 8;
    while (nchunk > 1 && fixed + (size_t)nchunk * MROWS * PLD * 2 > ws_size) nchunk >>= 1;
    u16* partial = (u16*)p;

    dim3 blk(256);
    init_kernel<<<dim3(772), blk, 0, stream>>>(A, AbitsT, W1w, W1b, a1, W2w, W2b,
                                               W3w, W3b, a2, Cwf, cbf, va1, vc1,
                                               va2, vc2, dmu);

    auto launch_attn = [&](const u16* WhT, const float* srcT, const float* dstT,
                           const u32* dm, u16* part, float* oF) {
        if (nchunk == 8)
            attn_kernel<8><<<dim3(64, 8), dim3(512), 0, stream>>>(WhT, srcT, dstT, AbitsT, dm, part, oF);
        else if (nchunk == 4)
            attn_kernel<16><<<dim3(64, 4), dim3(512), 0, stream>>>(WhT, srcT, dstT, AbitsT, dm, part, oF);
        else if (nchunk == 2)
            attn_kernel<32><<<dim3(64, 2), dim3(512), 0, stream>>>(WhT, srcT, dstT, AbitsT, dm, part, oF);
        else
            attn_kernel<64><<<dim3(64, 1), dim3(512), 0, stream>>>(WhT, srcT, dstT, AbitsT, dm, nullptr, oF);
    };

    // ---- layer 1 ----
    gemm16<<<dim3(64, 4), blk, 0, stream>>>(hIn, W1w, W1b, WhT1, 512);
    srcdst_kernel<<<dim3(128), blk, 0, stream>>>(hIn, 512, va1, vc1, srcT1, dstT1, dmu);
    launch_attn(WhT1, srcT1, dstT1, dmu, nchunk > 1 ? partial : nullptr,
                nchunk > 1 ? nullptr : x1f);
    if (nchunk > 1)
        combine_kernel<<<dim3(4096), blk, 0, stream>>>(partial, nchunk, x1f);

    // ---- layer 2 (W3∘W2 fused into Cwf; scores exact from x1f via va2) ----
    gemm16<<<dim3(64, 4), blk, 0, stream>>>(x1f, Cwf, cbf, WhT2, 256);
    srcdst_kernel<<<dim3(128), blk, 0, stream>>>(x1f, 256, va2, vc2, srcT2, dstT2, dmu + 4);
    launch_attn(WhT2, srcT2, dstT2, dmu + 4, nchunk > 1 ? partial : nullptr,
                nchunk > 1 ? nullptr : outX);
    if (nchunk > 1)
        combine_kernel<<<dim3(4096), blk, 0, stream>>>(partial, nchunk, outX);

    // ---- classifier head ----
    cls_kernel<<<dim3((MROWS * NCLS + 255) / 256), blk, 0, stream>>>(
        outX, FLw, FLb, outL);
}

// Round 9
// 206.234 us; speedup vs baseline: 1.1400x; 1.1400x over previous
//
#include <hip/hip_runtime.h>
#include <hip/hip_bf16.h>

typedef _Float16 f16_t;
typedef unsigned short u16;
typedef unsigned int u32;
typedef float f32x4 __attribute__((ext_vector_type(4)));
typedef f16_t f16x8 __attribute__((ext_vector_type(8)));
typedef u16 u16x8 __attribute__((ext_vector_type(8)));
typedef u16 u16x4 __attribute__((ext_vector_type(4)));

#define MROWS 4096
#define NHEADS 4
#define COUT 64
#define OHF 256   // NHEADS*COUT
#define NCLS 40
#define LOG2E 1.4426950408889634f
#define PLD 264   // partial row length (u16): 256 acc + 4 rowsum + pad

static __device__ __forceinline__ u16 f16b(float x) {
    return __builtin_bit_cast(u16, (f16_t)x);
}
static __device__ __forceinline__ float f16f(u16 x) {
    return (float)__builtin_bit_cast(f16_t, x);
}

// ---------------- init: A->AbitsT (transposed bitmask) + prep (Cw, va1, va2, dmu) ----------------
// blocks 0..2047: bits (2 rows each; 4 independent loads per ballot round)
// blocks 2048..2307: prep
__global__ __launch_bounds__(256) void init_kernel(const int* __restrict__ A,
                                                   u32* __restrict__ AbitsT,
                                                   const float* __restrict__ W1w,
                                                   const float* __restrict__ W1b,
                                                   const float* __restrict__ a1,
                                                   const float* __restrict__ W2w,
                                                   const float* __restrict__ W2b,
                                                   const float* __restrict__ W3w,
                                                   const float* __restrict__ W3b,
                                                   const float* __restrict__ a2,
                                                   float* __restrict__ Cwf,
                                                   float* __restrict__ cbf,
                                                   float* __restrict__ va1,
                                                   float* __restrict__ vc1,
                                                   float* __restrict__ va2,
                                                   float* __restrict__ vc2,
                                                   u32* __restrict__ dmu) {
    __shared__ u32 W[2][128];
    __shared__ float u[8][64];
    const int bx = blockIdx.x, tid = threadIdx.x;
    if (bx < 2048) {
        const int i0 = bx * 2;
        const int lane = tid & 63, wv = tid >> 6;
        // 2 rows x 16 j-groups (256 j each) = 32 tasks over 4 waves; 4 indep loads/task
        for (int t = wv; t < 32; t += 4) {
            const int r = t >> 4, q = t & 15;
            const size_t base = (size_t)(i0 + r) * MROWS + q * 256 + lane;
            const int a0 = A[base];
            const int a1_ = A[base + 64];
            const int a2_ = A[base + 128];
            const int a3 = A[base + 192];
            const unsigned long long b0 = __ballot(a0 != 0);
            const unsigned long long b1 = __ballot(a1_ != 0);
            const unsigned long long b2 = __ballot(a2_ != 0);
            const unsigned long long b3 = __ballot(a3 != 0);
            if (lane == 0) {
                W[r][q * 8 + 0] = (u32)b0;
                W[r][q * 8 + 2] = (u32)b1;
                W[r][q * 8 + 4] = (u32)b2;
                W[r][q * 8 + 6] = (u32)b3;
            } else if (lane == 1) {
                W[r][q * 8 + 1] = (u32)(b0 >> 32);
                W[r][q * 8 + 3] = (u32)(b1 >> 32);
                W[r][q * 8 + 5] = (u32)(b2 >> 32);
                W[r][q * 8 + 7] = (u32)(b3 >> 32);
            }
        }
        __syncthreads();
        // transposed write: AbitsT[jw*4096 + i]
        {
            const int jw = tid >> 1, r = tid & 1;
            AbitsT[(size_t)jw * MROWS + i0 + r] = W[r][jw];
        }
        return;
    }
    const int bid = bx - 2048;
    if (bid < 256) {
        float acc = 0.f;
        for (int t = 0; t < 64; ++t)
            acc += W2w[bid * 64 + t] * W3w[t * 256 + tid];
        Cwf[bid * 256 + tid] = acc;
        if (tid == 0) {
            float b = 0.f;
            for (int t = 0; t < 64; ++t) b += W2w[bid * 64 + t] * W3b[t];
            cbf[bid] = b + W2b[bid];
        }
    } else if (bid < 258) {
        const int k = (bid - 256) * 256 + tid;
#pragma unroll
        for (int hs = 0; hs < 8; ++hs) {
            const int h = hs >> 1, s = hs & 1;
            float acc = 0.f;
            for (int c = 0; c < COUT; ++c)
                acc += W1w[(size_t)(h * COUT + c) * 512 + k] * a1[h * 128 + s * COUT + c];
            va1[hs * 512 + k] = acc;
        }
        if (bid == 256 && tid == 0) {
            for (int hs = 0; hs < 8; ++hs) {
                const int h = hs >> 1, s = hs & 1;
                float b = 0.f;
                for (int c = 0; c < COUT; ++c) b += W1b[h * COUT + c] * a1[h * 128 + s * COUT + c];
                vc1[hs] = b;
            }
        }
    } else if (bid == 258) {
#pragma unroll
        for (int e = tid * 2; e < tid * 2 + 2; ++e) {
            const int hs = e >> 6, t = e & 63;
            const int h = hs >> 1, s = hs & 1;
            float acc = 0.f;
            for (int c = 0; c < COUT; ++c)
                acc += W2w[(size_t)(h * COUT + c) * 64 + t] * a2[h * 128 + s * COUT + c];
            u[hs][t] = acc;
        }
        __syncthreads();
#pragma unroll
        for (int hs = 0; hs < 8; ++hs) {
            float acc = 0.f;
            for (int t = 0; t < 64; ++t) acc += u[hs][t] * W3w[t * 256 + tid];
            va2[hs * 256 + tid] = acc;
        }
        if (tid == 0) {
            for (int hs = 0; hs < 8; ++hs) {
                const int h = hs >> 1, s = hs & 1;
                float b = 0.f;
                for (int t = 0; t < 64; ++t) b += u[hs][t] * W3b[t];
                for (int c = 0; c < COUT; ++c) b += W2b[h * COUT + c] * a2[h * 128 + s * COUT + c];
                vc2[hs] = b;
            }
        }
    } else {
        if (tid < 8) dmu[tid] = 0u;   // monotone-mapped -inf
    }
}

// ---------------- GEMM: WhT[n][m] = f16( sum_k A[m,k]*B[n,k] + bias[n] ) ----------------
__global__ __launch_bounds__(256) void gemm16(const float* __restrict__ A,
                                              const float* __restrict__ B,
                                              const float* __restrict__ bias,
                                              u16* __restrict__ WhT, int K) {
    __shared__ u16 Al[64][40];
    __shared__ u16 Bl[64][40];
    const int tid = threadIdx.x;
    const int lane = tid & 63, wv = tid >> 6;
    const int l15 = lane & 15, g = lane >> 4;
    const int m0 = blockIdx.x * 64, n0 = blockIdx.y * 64;
    const int r = tid >> 2, c8 = (tid & 3) * 8;

    f32x4 acc[4] = {};
    for (int k0 = 0; k0 < K; k0 += 32) {
        const float4 a0 = *(const float4*)&A[(size_t)(m0 + r) * K + k0 + c8];
        const float4 a1 = *(const float4*)&A[(size_t)(m0 + r) * K + k0 + c8 + 4];
        const float4 b0 = *(const float4*)&B[(size_t)(n0 + r) * K + k0 + c8];
        const float4 b1 = *(const float4*)&B[(size_t)(n0 + r) * K + k0 + c8 + 4];
        u16x8 av, bv;
        av[0] = f16b(a0.x); av[1] = f16b(a0.y); av[2] = f16b(a0.z); av[3] = f16b(a0.w);
        av[4] = f16b(a1.x); av[5] = f16b(a1.y); av[6] = f16b(a1.z); av[7] = f16b(a1.w);
        bv[0] = f16b(b0.x); bv[1] = f16b(b0.y); bv[2] = f16b(b0.z); bv[3] = f16b(b0.w);
        bv[4] = f16b(b1.x); bv[5] = f16b(b1.y); bv[6] = f16b(b1.z); bv[7] = f16b(b1.w);
        __syncthreads();
        *(u16x8*)&Al[r][c8] = av;
        *(u16x8*)&Bl[r][c8] = bv;
        __syncthreads();
        f16x8 afr = *(const f16x8*)&Al[16 * wv + l15][8 * g];
#pragma unroll
        for (int ni = 0; ni < 4; ++ni) {
            f16x8 bfr = *(const f16x8*)&Bl[16 * ni + l15][8 * g];
            acc[ni] = __builtin_amdgcn_mfma_f32_16x16x32_f16(afr, bfr, acc[ni], 0, 0, 0);
        }
    }
#pragma unroll
    for (int ni = 0; ni < 4; ++ni) {
        const int n = n0 + 16 * ni + l15;
        const float bvs = bias[n];
        u16x4 pv;
#pragma unroll
        for (int rr = 0; rr < 4; ++rr) pv[rr] = f16b(acc[ni][rr] + bvs);
        *(u16x4*)&WhT[(size_t)n * MROWS + m0 + 16 * wv + 4 * g] = pv;
    }
}

// ---------------- scores: 16 rows x 16 k-slices, fused per-head dst max ----------------
__global__ __launch_bounds__(256) void srcdst_kernel(const float* __restrict__ X, int K,
                                                     const float* __restrict__ va,
                                                     const float* __restrict__ vc,
                                                     float* __restrict__ srcT,
                                                     float* __restrict__ dstT,
                                                     u32* __restrict__ dmu) {
    __shared__ float red[16][16][9];   // [row][ki][hs] (padded)
    __shared__ float dred[4][16];
    const int tid = threadIdx.x;
    const int ii = tid >> 4, ki = tid & 15;
    const int i = blockIdx.x * 16 + ii;
    const int KS = K >> 4;
    const int k0 = ki * KS;
    float acc[8] = {};
    for (int k = k0; k < k0 + KS; k += 4) {
        const float4 xv = *(const float4*)&X[(size_t)i * K + k];
#pragma unroll
        for (int hs = 0; hs < 8; ++hs) {
            const float4 vv = *(const float4*)&va[(size_t)hs * K + k];
            acc[hs] += xv.x * vv.x + xv.y * vv.y + xv.z * vv.z + xv.w * vv.w;
        }
    }
#pragma unroll
    for (int hs = 0; hs < 8; ++hs) red[ii][ki][hs] = acc[hs];
    __syncthreads();
    if (tid < 128) {
        const int row = tid >> 3, hs = tid & 7, h = hs >> 1;
        float sum = 0.f;
#pragma unroll
        for (int kk = 0; kk < 16; ++kk) sum += red[row][kk][hs];
        const float val = sum + vc[hs];
        const int ig = blockIdx.x * 16 + row;
        if ((hs & 1) == 0) {
            srcT[h * MROWS + ig] = val;
        } else {
            dstT[h * MROWS + ig] = val;
            dred[h][row] = val;
        }
    }
    __syncthreads();
    if (tid < 4) {
        float m = -3.4e38f;
#pragma unroll
        for (int r = 0; r < 16; ++r) m = fmaxf(m, dred[tid][r]);
        const u32 b = __builtin_bit_cast(u32, m);
        const u32 key = (b & 0x80000000u) ? ~b : (b | 0x80000000u);
        atomicMax(dmu + tid, key);
    }
}

// ---------------- attention (f16 MFMA, factorized exp, ones-MFMA rowsum) ----------------
// grid (64, nchunk), 512 thr (8 waves: wave = (h, row-half)). 64 i-rows per block.
// w' = mask ? (t>=0 ? F1_i*G1_j : F2_i*G2_j) : 0, shifted so w' <= 1.
template <int JT>
__global__ __launch_bounds__(512) void attn_kernel(const u16* __restrict__ WhT,
                                                   const float* __restrict__ srcT,
                                                   const float* __restrict__ dstT,
                                                   const u32* __restrict__ AbitsT,
                                                   const u32* __restrict__ dmu,
                                                   u16* __restrict__ partial,
                                                   float* __restrict__ outF) {
    __shared__ __align__(16) unsigned char whL[256 * 128];   // 32 KB swizzled [c][j]
    const int tid = threadIdx.x;
    const int lane = tid & 63, w = tid >> 6;
    const int h = w & 3, half = w >> 2;
    const int l15 = lane & 15, g = lane >> 4;
    const int i0 = blockIdx.x * 64;
    const int chunk = blockIdx.y;
    const int xorm = (l15 & 7) << 4;          // read-side swizzle

    const u32 ku = dmu[h];
    const u32 fb = (ku & 0x80000000u) ? (ku ^ 0x80000000u) : ~ku;
    const float dmh = __builtin_bit_cast(float, fb);

    float negs_[2], F1_[2], F2_[2];
    f32x4 acc[2][4] = {};
    f32x4 acc1[2] = {};
    f16x8 ones;
#pragma unroll
    for (int e = 0; e < 8; ++e) ones[e] = (f16_t)1.0f;
#pragma unroll
    for (int mi = 0; mi < 2; ++mi) {
        const float s = srcT[h * MROWS + i0 + 32 * half + 16 * mi + l15];
        const float sd = s + dmh;
        const float C = fmaxf(sd, 0.01f * sd);
        negs_[mi] = -s;
        F1_[mi] = __builtin_amdgcn_exp2f((sd - C) * LOG2E);          // exp(s+dmh-C)
        F2_[mi] = __builtin_amdgcn_exp2f((0.01f * sd - C) * LOG2E);  // exp(.01(s+dmh)-C)
    }

    for (int jt = 0; jt < JT; ++jt) {
        const int j0 = (chunk * JT + jt) * 64;
        // ---- stage Wh tile: 256 c x 64 j, coalesced 16B chunks, swizzled LDS ----
        __syncthreads();
#pragma unroll
        for (int q = 0; q < 4; ++q) {
            const int eid = tid + 512 * q;
            const int c = eid >> 3, jo8 = eid & 7;
            u16x8 v = *(const u16x8*)&WhT[(size_t)c * MROWS + j0 + jo8 * 8];
            *(u16x8*)(whL + c * 128 + ((jo8 * 16) ^ ((c & 7) << 4))) = v;
        }
        __syncthreads();
        f16x8 af[2];
#pragma unroll
        for (int kj = 0; kj < 2; ++kj) {
            const int jk = j0 + 32 * kj + 8 * g;
            const float4 d0 = *(const float4*)&dstT[h * MROWS + jk];
            const float4 d1 = *(const float4*)&dstT[h * MROWS + jk + 4];
            float dv[8] = {d0.x, d0.y, d0.z, d0.w, d1.x, d1.y, d1.z, d1.w};
            // shared G factors (per-j, shared across both mi halves)
            float G1[8], G2[8];
#pragma unroll
            for (int e = 0; e < 8; ++e) {
                const float uu = dv[e] - dmh;
                G1[e] = __builtin_amdgcn_exp2f(uu * LOG2E);           // exp(d-dmh)
                G2[e] = __builtin_amdgcn_exp2f(uu * (0.01f * LOG2E)); // exp(.01(d-dmh))
            }
#pragma unroll
            for (int mi = 0; mi < 2; ++mi) {
                const int irow = i0 + 32 * half + 16 * mi + l15;
                const u32 word = AbitsT[(size_t)((j0 >> 5) + kj) * MROWS + irow];
                const u32 bits = (word >> (8 * g)) & 0xffu;
                f16x8 a;
#pragma unroll
                for (int e = 0; e < 8; ++e) {
                    const bool pos = dv[e] >= negs_[mi];
                    float wv = (pos ? G1[e] : G2[e]) * (pos ? F1_[mi] : F2_[mi]);
                    wv = ((bits >> e) & 1u) ? wv : 0.f;
                    a[e] = (f16_t)wv;
                }
                af[mi] = a;
            }
            // ---- MFMAs: B-fragments from swizzled LDS + ones-column rowsum ----
#pragma unroll
            for (int ni = 0; ni < 4; ++ni) {
                const int c = h * COUT + 16 * ni + l15;
                f16x8 b = *(const f16x8*)(whL + c * 128 + ((64 * kj + 16 * g) ^ xorm));
                acc[0][ni] = __builtin_amdgcn_mfma_f32_16x16x32_f16(af[0], b, acc[0][ni], 0, 0, 0);
                acc[1][ni] = __builtin_amdgcn_mfma_f32_16x16x32_f16(af[1], b, acc[1][ni], 0, 0, 0);
            }
            acc1[0] = __builtin_amdgcn_mfma_f32_16x16x32_f16(af[0], ones, acc1[0], 0, 0, 0);
            acc1[1] = __builtin_amdgcn_mfma_f32_16x16x32_f16(af[1], ones, acc1[1], 0, 0, 0);
        }
    }

    if (partial) {
        u16* pc = partial + (size_t)chunk * MROWS * PLD;
#pragma unroll
        for (int mi = 0; mi < 2; ++mi) {
#pragma unroll
            for (int ni = 0; ni < 4; ++ni)
#pragma unroll
                for (int rr = 0; rr < 4; ++rr) {
                    const int i = i0 + 32 * half + 16 * mi + 4 * g + rr;
                    pc[(size_t)i * PLD + h * COUT + 16 * ni + l15] = f16b(acc[mi][ni][rr]);
                }
#pragma unroll
            for (int rr = 0; rr < 4; ++rr)
                if (l15 == rr)
                    pc[(size_t)(i0 + 32 * half + 16 * mi + 4 * g + rr) * PLD + 256 + h] =
                        f16b(acc1[mi][rr]);
        }
    } else {
#pragma unroll
        for (int mi = 0; mi < 2; ++mi)
#pragma unroll
            for (int rr = 0; rr < 4; ++rr) {
                const int i = i0 + 32 * half + 16 * mi + 4 * g + rr;
                const float rs = acc1[mi][rr];
#pragma unroll
                for (int ni = 0; ni < 4; ++ni)
                    outF[(size_t)i * OHF + h * COUT + 16 * ni + l15] = acc[mi][ni][rr] / rs;
            }
    }
}

// ---------------- combine chunked f16 partials: block = one row ----------------
__global__ __launch_bounds__(256) void combine_kernel(const u16* __restrict__ partial,
                                                      int nchunk,
                                                      float* __restrict__ outF) {
    const int i = blockIdx.x, c = threadIdx.x, h = c >> 6;
    float v = 0.f, rs = 0.f;
    for (int ch = 0; ch < nchunk; ++ch) {
        const u16* pc = partial + (size_t)ch * MROWS * PLD + (size_t)i * PLD;
        v += f16f(pc[c]);
        rs += f16f(pc[256 + h]);
    }
    outF[(size_t)i * OHF + c] = v / rs;
}

// ---------------- classifier head, fp32 VALU ----------------
__global__ __launch_bounds__(256) void cls_kernel(const float* __restrict__ xf,
                                                  const float* __restrict__ FLw,
                                                  const float* __restrict__ FLb,
                                                  float* __restrict__ out1) {
    const int id = blockIdx.x * 256 + threadIdx.x;
    if (id >= MROWS * NCLS) return;
    const int m = id / NCLS, k = id - m * NCLS;
    float acc = FLb[k];
    for (int c = 0; c < OHF; c += 4) {
        const float4 xv = *(const float4*)&xf[(size_t)m * OHF + c];
        const float4 wv = *(const float4*)&FLw[(size_t)k * OHF + c];
        acc += xv.x * wv.x + xv.y * wv.y + xv.z * wv.z + xv.w * wv.w;
    }
    out1[id] = acc;
}

extern "C" void kernel_launch(void* const* d_in, const int* in_sizes, int n_in,
                              void* d_out, int out_size, void* d_ws, size_t ws_size,
                              hipStream_t stream) {
    const float* hIn = (const float*)d_in[0];
    const int*   A   = (const int*)d_in[1];
    const float* W1w = (const float*)d_in[2];
    const float* W1b = (const float*)d_in[3];
    const float* a1  = (const float*)d_in[4];
    const float* W3w = (const float*)d_in[5];
    const float* W3b = (const float*)d_in[6];
    const float* W2w = (const float*)d_in[7];
    const float* W2b = (const float*)d_in[8];
    const float* a2  = (const float*)d_in[9];
    const float* FLw = (const float*)d_in[10];
    const float* FLb = (const float*)d_in[11];
    float* outX = (float*)d_out;                     // x: (4096 x 256) fp32
    float* outL = outX + (size_t)MROWS * OHF;        // logits: (4096 x 40) fp32

    char* p = (char*)d_ws;
    auto alloc = [&](size_t bytes) { char* q = p; p += (bytes + 255) & ~(size_t)255; return q; };
    u32*   AbitsT = (u32*)alloc((size_t)MROWS * 128 * 4);
    u16*   WhT1  = (u16*)alloc((size_t)OHF * MROWS * 2);
    u16*   WhT2  = (u16*)alloc((size_t)OHF * MROWS * 2);
    float* x1f   = (float*)alloc((size_t)MROWS * OHF * 4);
    float* Cwf   = (float*)alloc((size_t)256 * 256 * 4);
    float* cbf   = (float*)alloc(256 * 4);
    float* va1   = (float*)alloc((size_t)8 * 512 * 4);
    float* vc1   = (float*)alloc(8 * 4);
    float* va2   = (float*)alloc((size_t)8 * 256 * 4);
    float* vc2   = (float*)alloc(8 * 4);
    float* srcT1 = (float*)alloc((size_t)NHEADS * MROWS * 4);
    float* dstT1 = (float*)alloc((size_t)NHEADS * MROWS * 4);
    float* srcT2 = (float*)alloc((size_t)NHEADS * MROWS * 4);
    float* dstT2 = (float*)alloc((size_t)NHEADS * MROWS * 4);
    u32*   dmu   = (u32*)alloc(8 * 4);               // [0..3]=layer1, [4..7]=layer2
    size_t fixed = (size_t)(p - (char*)d_ws);
    int nchunk = 8;
    while (nchunk > 1 && fixed + (size_t)nchunk * MROWS * PLD * 2 > ws_size) nchunk >>= 1;
    u16* partial = (u16*)p;

    dim3 blk(256);
    init_kernel<<<dim3(2308), blk, 0, stream>>>(A, AbitsT, W1w, W1b, a1, W2w, W2b,
                                                W3w, W3b, a2, Cwf, cbf, va1, vc1,
                                                va2, vc2, dmu);

    auto launch_attn = [&](const u16* WhT, const float* srcT, const float* dstT,
                           const u32* dm, u16* part, float* oF) {
        if (nchunk == 8)
            attn_kernel<8><<<dim3(64, 8), dim3(512), 0, stream>>>(WhT, srcT, dstT, AbitsT, dm, part, oF);
        else if (nchunk == 4)
            attn_kernel<16><<<dim3(64, 4), dim3(512), 0, stream>>>(WhT, srcT, dstT, AbitsT, dm, part, oF);
        else if (nchunk == 2)
            attn_kernel<32><<<dim3(64, 2), dim3(512), 0, stream>>>(WhT, srcT, dstT, AbitsT, dm, part, oF);
        else
            attn_kernel<64><<<dim3(64, 1), dim3(512), 0, stream>>>(WhT, srcT, dstT, AbitsT, dm, nullptr, oF);
    };

    // ---- layer 1 ----
    gemm16<<<dim3(64, 4), blk, 0, stream>>>(hIn, W1w, W1b, WhT1, 512);
    srcdst_kernel<<<dim3(256), blk, 0, stream>>>(hIn, 512, va1, vc1, srcT1, dstT1, dmu);
    launch_attn(WhT1, srcT1, dstT1, dmu, nchunk > 1 ? partial : nullptr,
                nchunk > 1 ? nullptr : x1f);
    if (nchunk > 1)
        combine_kernel<<<dim3(4096), blk, 0, stream>>>(partial, nchunk, x1f);

    // ---- layer 2 (W3∘W2 fused into Cwf; scores exact from x1f via va2) ----
    gemm16<<<dim3(64, 4), blk, 0, stream>>>(x1f, Cwf, cbf, WhT2, 256);
    srcdst_kernel<<<dim3(256), blk, 0, stream>>>(x1f, 256, va2, vc2, srcT2, dstT2, dmu + 4);
    launch_attn(WhT2, srcT2, dstT2, dmu + 4, nchunk > 1 ? partial : nullptr,
                nchunk > 1 ? nullptr : outX);
    if (nchunk > 1)
        combine_kernel<<<dim3(4096), blk, 0, stream>>>(partial, nchunk, outX);

    // ---- classifier head ----
    cls_kernel<<<dim3((MROWS * NCLS + 255) / 256), blk, 0, stream>>>(
        outX, FLw, FLb, outL);
}

// Round 11
// 183.495 us; speedup vs baseline: 1.2813x; 1.1239x over previous
//
#include <hip/hip_runtime.h>
#include <hip/hip_bf16.h>

typedef _Float16 f16_t;
typedef unsigned short u16;
typedef unsigned int u32;
typedef float f32x4 __attribute__((ext_vector_type(4)));
typedef f16_t f16x8 __attribute__((ext_vector_type(8)));
typedef u16 u16x8 __attribute__((ext_vector_type(8)));
typedef u16 u16x4 __attribute__((ext_vector_type(4)));

#define MROWS 4096
#define NHEADS 4
#define COUT 64
#define OHF 256   // NHEADS*COUT
#define NCLS 40
#define LOG2E 1.4426950408889634f
#define PLD 264   // partial row length (u16): 256 acc + 4 rowsum + pad

static __device__ __forceinline__ u16 f16b(float x) {
    return __builtin_bit_cast(u16, (f16_t)x);
}
static __device__ __forceinline__ float f16f(u16 x) {
    return (float)__builtin_bit_cast(f16_t, x);
}
static __device__ __forceinline__ float dmu_decode(u32 ku) {
    const u32 fb = (ku & 0x80000000u) ? (ku ^ 0x80000000u) : ~ku;
    return __builtin_bit_cast(float, fb);
}

// ---------------- init: A->AbitsT (transposed bitmask) + prep (Cw, va1, va2, dmu) ----------------
__global__ __launch_bounds__(256) void init_kernel(const int* __restrict__ A,
                                                   u32* __restrict__ AbitsT,
                                                   const float* __restrict__ W1w,
                                                   const float* __restrict__ W1b,
                                                   const float* __restrict__ a1,
                                                   const float* __restrict__ W2w,
                                                   const float* __restrict__ W2b,
                                                   const float* __restrict__ W3w,
                                                   const float* __restrict__ W3b,
                                                   const float* __restrict__ a2,
                                                   float* __restrict__ Cwf,
                                                   float* __restrict__ cbf,
                                                   float* __restrict__ va1,
                                                   float* __restrict__ vc1,
                                                   float* __restrict__ va2,
                                                   float* __restrict__ vc2,
                                                   u32* __restrict__ dmu) {
    __shared__ u32 W[2][128];
    __shared__ float u[8][64];
    const int bx = blockIdx.x, tid = threadIdx.x;
    if (bx < 2048) {
        const int i0 = bx * 2;
        const int lane = tid & 63, wv = tid >> 6;
        for (int t = wv; t < 32; t += 4) {
            const int r = t >> 4, q = t & 15;
            const size_t base = (size_t)(i0 + r) * MROWS + q * 256 + lane;
            const int a0 = A[base];
            const int a1_ = A[base + 64];
            const int a2_ = A[base + 128];
            const int a3 = A[base + 192];
            const unsigned long long b0 = __ballot(a0 != 0);
            const unsigned long long b1 = __ballot(a1_ != 0);
            const unsigned long long b2 = __ballot(a2_ != 0);
            const unsigned long long b3 = __ballot(a3 != 0);
            if (lane == 0) {
                W[r][q * 8 + 0] = (u32)b0;
                W[r][q * 8 + 2] = (u32)b1;
                W[r][q * 8 + 4] = (u32)b2;
                W[r][q * 8 + 6] = (u32)b3;
            } else if (lane == 1) {
                W[r][q * 8 + 1] = (u32)(b0 >> 32);
                W[r][q * 8 + 3] = (u32)(b1 >> 32);
                W[r][q * 8 + 5] = (u32)(b2 >> 32);
                W[r][q * 8 + 7] = (u32)(b3 >> 32);
            }
        }
        __syncthreads();
        {
            const int jw = tid >> 1, r = tid & 1;
            AbitsT[(size_t)jw * MROWS + i0 + r] = W[r][jw];
        }
        return;
    }
    const int bid = bx - 2048;
    if (bid < 256) {
        float acc = 0.f;
        for (int t = 0; t < 64; ++t)
            acc += W2w[bid * 64 + t] * W3w[t * 256 + tid];
        Cwf[bid * 256 + tid] = acc;
        if (tid == 0) {
            float b = 0.f;
            for (int t = 0; t < 64; ++t) b += W2w[bid * 64 + t] * W3b[t];
            cbf[bid] = b + W2b[bid];
        }
    } else if (bid < 258) {
        const int k = (bid - 256) * 256 + tid;
#pragma unroll
        for (int hs = 0; hs < 8; ++hs) {
            const int h = hs >> 1, s = hs & 1;
            float acc = 0.f;
            for (int c = 0; c < COUT; ++c)
                acc += W1w[(size_t)(h * COUT + c) * 512 + k] * a1[h * 128 + s * COUT + c];
            va1[hs * 512 + k] = acc;
        }
        if (bid == 256 && tid == 0) {
            for (int hs = 0; hs < 8; ++hs) {
                const int h = hs >> 1, s = hs & 1;
                float b = 0.f;
                for (int c = 0; c < COUT; ++c) b += W1b[h * COUT + c] * a1[h * 128 + s * COUT + c];
                vc1[hs] = b;
            }
        }
    } else if (bid == 258) {
#pragma unroll
        for (int e = tid * 2; e < tid * 2 + 2; ++e) {
            const int hs = e >> 6, t = e & 63;
            const int h = hs >> 1, s = hs & 1;
            float acc = 0.f;
            for (int c = 0; c < COUT; ++c)
                acc += W2w[(size_t)(h * COUT + c) * 64 + t] * a2[h * 128 + s * COUT + c];
            u[hs][t] = acc;
        }
        __syncthreads();
#pragma unroll
        for (int hs = 0; hs < 8; ++hs) {
            float acc = 0.f;
            for (int t = 0; t < 64; ++t) acc += u[hs][t] * W3w[t * 256 + tid];
            va2[hs * 256 + tid] = acc;
        }
        if (tid == 0) {
            for (int hs = 0; hs < 8; ++hs) {
                const int h = hs >> 1, s = hs & 1;
                float b = 0.f;
                for (int t = 0; t < 64; ++t) b += u[hs][t] * W3b[t];
                for (int c = 0; c < COUT; ++c) b += W2b[h * COUT + c] * a2[h * 128 + s * COUT + c];
                vc2[hs] = b;
            }
        }
    } else {
        if (tid < 8) dmu[tid] = 0u;   // monotone-mapped -inf
    }
}

// ---------------- proj: fused {gemm16 (blocks 0..255)} + {srcdst (blocks 256..511)} ----------------
__global__ __launch_bounds__(256) void proj_kernel(const float* __restrict__ X,
                                                   const float* __restrict__ Bm,
                                                   const float* __restrict__ bias,
                                                   int K,
                                                   u16* __restrict__ WhT,
                                                   const float* __restrict__ va,
                                                   const float* __restrict__ vc,
                                                   float* __restrict__ srcT,
                                                   float* __restrict__ dstT,
                                                   u32* __restrict__ dmu) {
    __shared__ u16 Al[64][40];
    __shared__ u16 Bl[64][40];
    __shared__ float red[16][16][9];
    __shared__ float dred[4][16];
    const int tid = threadIdx.x;
    if (blockIdx.x < 256) {
        // ---- GEMM: WhT[n][m] = f16(sum_k X[m,k]*Bm[n,k] + bias[n]) ----
        const int lane = tid & 63, wv = tid >> 6;
        const int l15 = lane & 15, g = lane >> 4;
        const int m0 = (blockIdx.x & 63) * 64, n0 = (blockIdx.x >> 6) * 64;
        const int r = tid >> 2, c8 = (tid & 3) * 8;
        f32x4 acc[4] = {};
        for (int k0 = 0; k0 < K; k0 += 32) {
            const float4 a0 = *(const float4*)&X[(size_t)(m0 + r) * K + k0 + c8];
            const float4 a1 = *(const float4*)&X[(size_t)(m0 + r) * K + k0 + c8 + 4];
            const float4 b0 = *(const float4*)&Bm[(size_t)(n0 + r) * K + k0 + c8];
            const float4 b1 = *(const float4*)&Bm[(size_t)(n0 + r) * K + k0 + c8 + 4];
            u16x8 av, bv;
            av[0] = f16b(a0.x); av[1] = f16b(a0.y); av[2] = f16b(a0.z); av[3] = f16b(a0.w);
            av[4] = f16b(a1.x); av[5] = f16b(a1.y); av[6] = f16b(a1.z); av[7] = f16b(a1.w);
            bv[0] = f16b(b0.x); bv[1] = f16b(b0.y); bv[2] = f16b(b0.z); bv[3] = f16b(b0.w);
            bv[4] = f16b(b1.x); bv[5] = f16b(b1.y); bv[6] = f16b(b1.z); bv[7] = f16b(b1.w);
            __syncthreads();
            *(u16x8*)&Al[r][c8] = av;
            *(u16x8*)&Bl[r][c8] = bv;
            __syncthreads();
            f16x8 afr = *(const f16x8*)&Al[16 * wv + l15][8 * g];
#pragma unroll
            for (int ni = 0; ni < 4; ++ni) {
                f16x8 bfr = *(const f16x8*)&Bl[16 * ni + l15][8 * g];
                acc[ni] = __builtin_amdgcn_mfma_f32_16x16x32_f16(afr, bfr, acc[ni], 0, 0, 0);
            }
        }
#pragma unroll
        for (int ni = 0; ni < 4; ++ni) {
            const int n = n0 + 16 * ni + l15;
            const float bvs = bias[n];
            u16x4 pv;
#pragma unroll
            for (int rr = 0; rr < 4; ++rr) pv[rr] = f16b(acc[ni][rr] + bvs);
            *(u16x4*)&WhT[(size_t)n * MROWS + m0 + 16 * wv + 4 * g] = pv;
        }
        return;
    }
    // ---- srcdst: 16 rows x 16 k-slices + fused per-head dst max ----
    const int bs = blockIdx.x - 256;
    const int ii = tid >> 4, ki = tid & 15;
    const int i = bs * 16 + ii;
    const int KS = K >> 4;
    const int k0 = ki * KS;
    float acc[8] = {};
    for (int k = k0; k < k0 + KS; k += 4) {
        const float4 xv = *(const float4*)&X[(size_t)i * K + k];
#pragma unroll
        for (int hs = 0; hs < 8; ++hs) {
            const float4 vv = *(const float4*)&va[(size_t)hs * K + k];
            acc[hs] += xv.x * vv.x + xv.y * vv.y + xv.z * vv.z + xv.w * vv.w;
        }
    }
#pragma unroll
    for (int hs = 0; hs < 8; ++hs) red[ii][ki][hs] = acc[hs];
    __syncthreads();
    if (tid < 128) {
        const int row = tid >> 3, hs = tid & 7, h = hs >> 1;
        float sum = 0.f;
#pragma unroll
        for (int kk = 0; kk < 16; ++kk) sum += red[row][kk][hs];
        const float val = sum + vc[hs];
        const int ig = bs * 16 + row;
        if ((hs & 1) == 0) {
            srcT[h * MROWS + ig] = val;
        } else {
            dstT[h * MROWS + ig] = val;
            dred[h][row] = val;
        }
    }
    __syncthreads();
    if (tid < 4) {
        float m = -3.4e38f;
#pragma unroll
        for (int r = 0; r < 16; ++r) m = fmaxf(m, dred[tid][r]);
        const u32 b = __builtin_bit_cast(u32, m);
        const u32 key = (b & 0x80000000u) ? ~b : (b | 0x80000000u);
        atomicMax(dmu + tid, key);
    }
}

// ---------------- attention: R9-exact scalar scoring + f32 LDS G tables (hoisted exps) ----------------
// w' = mask ? exp(lrelu(s+d) - C_i) : 0 via branch select (pos ? G1*F1 : G2*F2), f32 mul, single f16 cvt.
template <int JT>
__global__ __launch_bounds__(512) void attn_kernel(const u16* __restrict__ WhT,
                                                   const float* __restrict__ srcT,
                                                   const float* __restrict__ dstT,
                                                   const u32* __restrict__ AbitsT,
                                                   const u32* __restrict__ dmu,
                                                   u16* __restrict__ partial,
                                                   float* __restrict__ outF) {
    constexpr int J64 = JT * 64;                    // j's per chunk
    __shared__ __align__(16) unsigned char whL[256 * 128];   // 32 KB swizzled [c][j]
    __shared__ __align__(16) float GT[8 * J64];     // [(h*2+br)][j] f32 exps
    const int tid = threadIdx.x;
    const int lane = tid & 63, w = tid >> 6;
    const int h = w & 3, half = w >> 2;
    const int l15 = lane & 15, g = lane >> 4;
    const int i0 = blockIdx.x * 64;
    const int chunk = blockIdx.y;
    const int jbase = chunk * J64;
    const int xorm = (l15 & 7) << 4;

    // ---- prologue: G tables (once per block; bit-identical values to per-lane recompute) ----
    for (int e = tid; e < 8 * J64; e += 512) {
        const int hb = e / J64;                     // h*2 + br
        const int j = e - hb * J64;
        const float dmhe = dmu_decode(dmu[hb >> 1]);
        const float sc = (hb & 1) ? 0.01f * LOG2E : LOG2E;
        GT[e] = __builtin_amdgcn_exp2f((dstT[(hb >> 1) * MROWS + jbase + j] - dmhe) * sc);
    }

    // ---- per-row F factors (f32, as R9) ----
    const float dmh = dmu_decode(dmu[h]);
    float negs_[2], F1_[2], F2_[2];
#pragma unroll
    for (int mi = 0; mi < 2; ++mi) {
        const float s = srcT[h * MROWS + i0 + 32 * half + 16 * mi + l15];
        const float sd = s + dmh;
        const float C = fmaxf(sd, 0.01f * sd);
        negs_[mi] = -s;
        F1_[mi] = __builtin_amdgcn_exp2f((sd - C) * LOG2E);
        F2_[mi] = __builtin_amdgcn_exp2f((0.01f * sd - C) * LOG2E);
    }

    f32x4 acc[2][4] = {};
    f32x4 acc1[2] = {};
    f16x8 ones;
#pragma unroll
    for (int e = 0; e < 8; ++e) ones[e] = (f16_t)1.0f;

    for (int jt = 0; jt < JT; ++jt) {
        const int j0 = jbase + jt * 64;
        __syncthreads();   // covers prologue on first iteration
#pragma unroll
        for (int q = 0; q < 4; ++q) {
            const int eid = tid + 512 * q;
            const int c = eid >> 3, jo8 = eid & 7;
            u16x8 v = *(const u16x8*)&WhT[(size_t)c * MROWS + j0 + jo8 * 8];
            *(u16x8*)(whL + c * 128 + ((jo8 * 16) ^ ((c & 7) << 4))) = v;
        }
        __syncthreads();
        f16x8 af[2];
#pragma unroll
        for (int kj = 0; kj < 2; ++kj) {
            const int jk = j0 + 32 * kj + 8 * g;
            const float4 d0 = *(const float4*)&dstT[h * MROWS + jk];
            const float4 d1 = *(const float4*)&dstT[h * MROWS + jk + 4];
            float dv[8] = {d0.x, d0.y, d0.z, d0.w, d1.x, d1.y, d1.z, d1.w};
            const int goff = jt * 64 + 32 * kj + 8 * g;
            const float4 g10 = *(const float4*)&GT[(h * 2) * J64 + goff];
            const float4 g11 = *(const float4*)&GT[(h * 2) * J64 + goff + 4];
            const float4 g20 = *(const float4*)&GT[(h * 2 + 1) * J64 + goff];
            const float4 g21 = *(const float4*)&GT[(h * 2 + 1) * J64 + goff + 4];
            const float G1[8] = {g10.x, g10.y, g10.z, g10.w, g11.x, g11.y, g11.z, g11.w};
            const float G2[8] = {g20.x, g20.y, g20.z, g20.w, g21.x, g21.y, g21.z, g21.w};
#pragma unroll
            for (int mi = 0; mi < 2; ++mi) {
                const int irow = i0 + 32 * half + 16 * mi + l15;
                const u32 word = AbitsT[(size_t)((j0 >> 5) + kj) * MROWS + irow];
                const u32 bits = (word >> (8 * g)) & 0xffu;
                f16x8 a;
#pragma unroll
                for (int e = 0; e < 8; ++e) {
                    const bool pos = dv[e] >= negs_[mi];
                    float wv = (pos ? G1[e] : G2[e]) * (pos ? F1_[mi] : F2_[mi]);
                    wv = ((bits >> e) & 1u) ? wv : 0.f;
                    a[e] = (f16_t)wv;
                }
                af[mi] = a;
            }
#pragma unroll
            for (int ni = 0; ni < 4; ++ni) {
                const int c = h * COUT + 16 * ni + l15;
                f16x8 b = *(const f16x8*)(whL + c * 128 + ((64 * kj + 16 * g) ^ xorm));
                acc[0][ni] = __builtin_amdgcn_mfma_f32_16x16x32_f16(af[0], b, acc[0][ni], 0, 0, 0);
                acc[1][ni] = __builtin_amdgcn_mfma_f32_16x16x32_f16(af[1], b, acc[1][ni], 0, 0, 0);
            }
            acc1[0] = __builtin_amdgcn_mfma_f32_16x16x32_f16(af[0], ones, acc1[0], 0, 0, 0);
            acc1[1] = __builtin_amdgcn_mfma_f32_16x16x32_f16(af[1], ones, acc1[1], 0, 0, 0);
        }
    }

    if (partial) {
        u16* pc = partial + (size_t)chunk * MROWS * PLD;
#pragma unroll
        for (int mi = 0; mi < 2; ++mi) {
#pragma unroll
            for (int ni = 0; ni < 4; ++ni)
#pragma unroll
                for (int rr = 0; rr < 4; ++rr) {
                    const int i = i0 + 32 * half + 16 * mi + 4 * g + rr;
                    pc[(size_t)i * PLD + h * COUT + 16 * ni + l15] = f16b(acc[mi][ni][rr]);
                }
#pragma unroll
            for (int rr = 0; rr < 4; ++rr)
                if (l15 == rr)
                    pc[(size_t)(i0 + 32 * half + 16 * mi + 4 * g + rr) * PLD + 256 + h] =
                        f16b(acc1[mi][rr]);
        }
    } else {
#pragma unroll
        for (int mi = 0; mi < 2; ++mi)
#pragma unroll
            for (int rr = 0; rr < 4; ++rr) {
                const int i = i0 + 32 * half + 16 * mi + 4 * g + rr;
                const float rs = acc1[mi][rr];
#pragma unroll
                for (int ni = 0; ni < 4; ++ni)
                    outF[(size_t)i * OHF + h * COUT + 16 * ni + l15] = acc[mi][ni][rr] / rs;
            }
    }
}

// ---------------- combine chunked f16 partials (+ optional fused classifier) ----------------
__global__ __launch_bounds__(256) void combine_kernel(const u16* __restrict__ partial,
                                                      int nchunk,
                                                      float* __restrict__ outF,
                                                      const float* __restrict__ FLw,
                                                      const float* __restrict__ FLb,
                                                      float* __restrict__ outL) {
    __shared__ float xrow[256];
    __shared__ float cred[40][4];
    const int i = blockIdx.x, c = threadIdx.x, h = c >> 6;
    float v = 0.f, rs = 0.f;
    for (int ch = 0; ch < nchunk; ++ch) {
        const u16* pc = partial + (size_t)ch * MROWS * PLD + (size_t)i * PLD;
        v += f16f(pc[c]);
        rs += f16f(pc[256 + h]);
    }
    const float r = v / rs;
    outF[(size_t)i * OHF + c] = r;
    if (!FLw) return;
    xrow[c] = r;
    __syncthreads();
    if (c < 160) {
        const int k = c >> 2, seg = c & 3;
        const float* xp = &xrow[seg * 64];
        const float* wp = &FLw[(size_t)k * OHF + seg * 64];
        float a = 0.f;
#pragma unroll
        for (int t = 0; t < 64; t += 4) {
            const float4 x4 = *(const float4*)&xp[t];
            const float4 w4 = *(const float4*)&wp[t];
            a += x4.x * w4.x + x4.y * w4.y + x4.z * w4.z + x4.w * w4.w;
        }
        cred[k][seg] = a;
    }
    __syncthreads();
    if (c < NCLS)
        outL[(size_t)i * NCLS + c] = cred[c][0] + cred[c][1] + cred[c][2] + cred[c][3] + FLb[c];
}

extern "C" void kernel_launch(void* const* d_in, const int* in_sizes, int n_in,
                              void* d_out, int out_size, void* d_ws, size_t ws_size,
                              hipStream_t stream) {
    const float* hIn = (const float*)d_in[0];
    const int*   A   = (const int*)d_in[1];
    const float* W1w = (const float*)d_in[2];
    const float* W1b = (const float*)d_in[3];
    const float* a1  = (const float*)d_in[4];
    const float* W3w = (const float*)d_in[5];
    const float* W3b = (const float*)d_in[6];
    const float* W2w = (const float*)d_in[7];
    const float* W2b = (const float*)d_in[8];
    const float* a2  = (const float*)d_in[9];
    const float* FLw = (const float*)d_in[10];
    const float* FLb = (const float*)d_in[11];
    float* outX = (float*)d_out;                     // x: (4096 x 256) fp32
    float* outL = outX + (size_t)MROWS * OHF;        // logits: (4096 x 40) fp32

    char* p = (char*)d_ws;
    auto alloc = [&](size_t bytes) { char* q = p; p += (bytes + 255) & ~(size_t)255; return q; };
    u32*   AbitsT = (u32*)alloc((size_t)MROWS * 128 * 4);
    u16*   WhT1  = (u16*)alloc((size_t)OHF * MROWS * 2);
    u16*   WhT2  = (u16*)alloc((size_t)OHF * MROWS * 2);
    float* x1f   = (float*)alloc((size_t)MROWS * OHF * 4);
    float* Cwf   = (float*)alloc((size_t)256 * 256 * 4);
    float* cbf   = (float*)alloc(256 * 4);
    float* va1   = (float*)alloc((size_t)8 * 512 * 4);
    float* vc1   = (float*)alloc(8 * 4);
    float* va2   = (float*)alloc((size_t)8 * 256 * 4);
    float* vc2   = (float*)alloc(8 * 4);
    float* srcT1 = (float*)alloc((size_t)NHEADS * MROWS * 4);
    float* dstT1 = (float*)alloc((size_t)NHEADS * MROWS * 4);
    float* srcT2 = (float*)alloc((size_t)NHEADS * MROWS * 4);
    float* dstT2 = (float*)alloc((size_t)NHEADS * MROWS * 4);
    u32*   dmu   = (u32*)alloc(8 * 4);               // [0..3]=layer1, [4..7]=layer2
    size_t fixed = (size_t)(p - (char*)d_ws);
    int nchunk = 8;
    if (fixed + (size_t)8 * MROWS * PLD * 2 > ws_size) nchunk = 4;
    u16* partial = (u16*)p;

    dim3 blk(256);
    init_kernel<<<dim3(2308), blk, 0, stream>>>(A, AbitsT, W1w, W1b, a1, W2w, W2b,
                                                W3w, W3b, a2, Cwf, cbf, va1, vc1,
                                                va2, vc2, dmu);

    auto launch_attn = [&](const u16* WhT, const float* srcT, const float* dstT,
                           const u32* dm) {
        if (nchunk == 8)
            attn_kernel<8><<<dim3(64, 8), dim3(512), 0, stream>>>(WhT, srcT, dstT, AbitsT, dm, partial, nullptr);
        else
            attn_kernel<16><<<dim3(64, 4), dim3(512), 0, stream>>>(WhT, srcT, dstT, AbitsT, dm, partial, nullptr);
    };

    // ---- layer 1 ----
    proj_kernel<<<dim3(512), blk, 0, stream>>>(hIn, W1w, W1b, 512, WhT1,
                                               va1, vc1, srcT1, dstT1, dmu);
    launch_attn(WhT1, srcT1, dstT1, dmu);
    combine_kernel<<<dim3(4096), blk, 0, stream>>>(partial, nchunk, x1f,
                                                   nullptr, nullptr, nullptr);

    // ---- layer 2 (W3∘W2 fused into Cwf; scores exact from x1f via va2) ----
    proj_kernel<<<dim3(512), blk, 0, stream>>>(x1f, Cwf, cbf, 256, WhT2,
                                               va2, vc2, srcT2, dstT2, dmu + 4);
    launch_attn(WhT2, srcT2, dstT2, dmu + 4);
    combine_kernel<<<dim3(4096), blk, 0, stream>>>(partial, nchunk, outX,
                                                   FLw, FLb, outL);
}

// Round 12
// 181.832 us; speedup vs baseline: 1.2930x; 1.0091x over previous
//
#include <hip/hip_runtime.h>
#include <hip/hip_bf16.h>

typedef _Float16 f16_t;
typedef unsigned short u16;
typedef unsigned int u32;
typedef float f32x4 __attribute__((ext_vector_type(4)));
typedef f16_t f16x8 __attribute__((ext_vector_type(8)));
typedef u16 u16x8 __attribute__((ext_vector_type(8)));
typedef u16 u16x4 __attribute__((ext_vector_type(4)));

#define MROWS 4096
#define NHEADS 4
#define COUT 64
#define OHF 256   // NHEADS*COUT
#define NCLS 40
#define LOG2E 1.4426950408889634f
#define PLD 264   // partial row length (u16): 256 acc + 4 rowsum + pad

static __device__ __forceinline__ u16 f16b(float x) {
    return __builtin_bit_cast(u16, (f16_t)x);
}
static __device__ __forceinline__ float f16f(u16 x) {
    return (float)__builtin_bit_cast(f16_t, x);
}
static __device__ __forceinline__ float dmu_decode(u32 ku) {
    const u32 fb = (ku & 0x80000000u) ? (ku ^ 0x80000000u) : ~ku;
    return __builtin_bit_cast(float, fb);
}

// ---------------- init: A->AbitsT (transposed bitmask) + prep (Cw, va1, va2, dmu) ----------------
__global__ __launch_bounds__(256) void init_kernel(const int* __restrict__ A,
                                                   u32* __restrict__ AbitsT,
                                                   const float* __restrict__ W1w,
                                                   const float* __restrict__ W1b,
                                                   const float* __restrict__ a1,
                                                   const float* __restrict__ W2w,
                                                   const float* __restrict__ W2b,
                                                   const float* __restrict__ W3w,
                                                   const float* __restrict__ W3b,
                                                   const float* __restrict__ a2,
                                                   float* __restrict__ Cwf,
                                                   float* __restrict__ cbf,
                                                   float* __restrict__ va1,
                                                   float* __restrict__ vc1,
                                                   float* __restrict__ va2,
                                                   float* __restrict__ vc2,
                                                   u32* __restrict__ dmu) {
    __shared__ u32 W[2][128];
    __shared__ float u[8][64];
    const int bx = blockIdx.x, tid = threadIdx.x;
    if (bx < 2048) {
        const int i0 = bx * 2;
        const int lane = tid & 63, wv = tid >> 6;
        for (int t = wv; t < 32; t += 4) {
            const int r = t >> 4, q = t & 15;
            const size_t base = (size_t)(i0 + r) * MROWS + q * 256 + lane;
            const int a0 = A[base];
            const int a1_ = A[base + 64];
            const int a2_ = A[base + 128];
            const int a3 = A[base + 192];
            const unsigned long long b0 = __ballot(a0 != 0);
            const unsigned long long b1 = __ballot(a1_ != 0);
            const unsigned long long b2 = __ballot(a2_ != 0);
            const unsigned long long b3 = __ballot(a3 != 0);
            if (lane == 0) {
                W[r][q * 8 + 0] = (u32)b0;
                W[r][q * 8 + 2] = (u32)b1;
                W[r][q * 8 + 4] = (u32)b2;
                W[r][q * 8 + 6] = (u32)b3;
            } else if (lane == 1) {
                W[r][q * 8 + 1] = (u32)(b0 >> 32);
                W[r][q * 8 + 3] = (u32)(b1 >> 32);
                W[r][q * 8 + 5] = (u32)(b2 >> 32);
                W[r][q * 8 + 7] = (u32)(b3 >> 32);
            }
        }
        __syncthreads();
        {
            const int jw = tid >> 1, r = tid & 1;
            AbitsT[(size_t)jw * MROWS + i0 + r] = W[r][jw];
        }
        return;
    }
    const int bid = bx - 2048;
    if (bid < 256) {
        float acc = 0.f;
        for (int t = 0; t < 64; ++t)
            acc += W2w[bid * 64 + t] * W3w[t * 256 + tid];
        Cwf[bid * 256 + tid] = acc;
        if (tid == 0) {
            float b = 0.f;
            for (int t = 0; t < 64; ++t) b += W2w[bid * 64 + t] * W3b[t];
            cbf[bid] = b + W2b[bid];
        }
    } else if (bid < 258) {
        const int k = (bid - 256) * 256 + tid;
#pragma unroll
        for (int hs = 0; hs < 8; ++hs) {
            const int h = hs >> 1, s = hs & 1;
            float acc = 0.f;
            for (int c = 0; c < COUT; ++c)
                acc += W1w[(size_t)(h * COUT + c) * 512 + k] * a1[h * 128 + s * COUT + c];
            va1[hs * 512 + k] = acc;
        }
        if (bid == 256 && tid == 0) {
            for (int hs = 0; hs < 8; ++hs) {
                const int h = hs >> 1, s = hs & 1;
                float b = 0.f;
                for (int c = 0; c < COUT; ++c) b += W1b[h * COUT + c] * a1[h * 128 + s * COUT + c];
                vc1[hs] = b;
            }
        }
    } else if (bid == 258) {
#pragma unroll
        for (int e = tid * 2; e < tid * 2 + 2; ++e) {
            const int hs = e >> 6, t = e & 63;
            const int h = hs >> 1, s = hs & 1;
            float acc = 0.f;
            for (int c = 0; c < COUT; ++c)
                acc += W2w[(size_t)(h * COUT + c) * 64 + t] * a2[h * 128 + s * COUT + c];
            u[hs][t] = acc;
        }
        __syncthreads();
#pragma unroll
        for (int hs = 0; hs < 8; ++hs) {
            float acc = 0.f;
            for (int t = 0; t < 64; ++t) acc += u[hs][t] * W3w[t * 256 + tid];
            va2[hs * 256 + tid] = acc;
        }
        if (tid == 0) {
            for (int hs = 0; hs < 8; ++hs) {
                const int h = hs >> 1, s = hs & 1;
                float b = 0.f;
                for (int t = 0; t < 64; ++t) b += u[hs][t] * W3b[t];
                for (int c = 0; c < COUT; ++c) b += W2b[h * COUT + c] * a2[h * 128 + s * COUT + c];
                vc2[hs] = b;
            }
        }
    } else {
        if (tid < 8) dmu[tid] = 0u;   // monotone-mapped -inf
    }
}

// ---------------- proj: fused {gemm16 -> fragment-major WhF} + {srcdst} ----------------
// WhF layout: chunk (jb, c, g) = 8 f16 of Wh^T[c][jb*32 + 8g .. +8] at u16 index ((jb*256+c)*4+g)*8
__global__ __launch_bounds__(256) void proj_kernel(const float* __restrict__ X,
                                                   const float* __restrict__ Bm,
                                                   const float* __restrict__ bias,
                                                   int K,
                                                   u16* __restrict__ WhF,
                                                   const float* __restrict__ va,
                                                   const float* __restrict__ vc,
                                                   float* __restrict__ srcT,
                                                   float* __restrict__ dstT,
                                                   u32* __restrict__ dmu) {
    __shared__ u16 Al[64][40];
    __shared__ u16 Bl[64][40];
    __shared__ u16 Tl[64][72];        // [n-local][m-local], padded: b128-aligned rows
    __shared__ float red[16][16][9];
    __shared__ float dred[4][16];
    const int tid = threadIdx.x;
    if (blockIdx.x < 256) {
        // ---- GEMM: fragment-major output ----
        const int lane = tid & 63, wv = tid >> 6;
        const int l15 = lane & 15, g = lane >> 4;
        const int m0 = (blockIdx.x & 63) * 64, n0 = (blockIdx.x >> 6) * 64;
        const int r = tid >> 2, c8 = (tid & 3) * 8;
        f32x4 acc[4] = {};
        for (int k0 = 0; k0 < K; k0 += 32) {
            const float4 a0 = *(const float4*)&X[(size_t)(m0 + r) * K + k0 + c8];
            const float4 a1 = *(const float4*)&X[(size_t)(m0 + r) * K + k0 + c8 + 4];
            const float4 b0 = *(const float4*)&Bm[(size_t)(n0 + r) * K + k0 + c8];
            const float4 b1 = *(const float4*)&Bm[(size_t)(n0 + r) * K + k0 + c8 + 4];
            u16x8 av, bv;
            av[0] = f16b(a0.x); av[1] = f16b(a0.y); av[2] = f16b(a0.z); av[3] = f16b(a0.w);
            av[4] = f16b(a1.x); av[5] = f16b(a1.y); av[6] = f16b(a1.z); av[7] = f16b(a1.w);
            bv[0] = f16b(b0.x); bv[1] = f16b(b0.y); bv[2] = f16b(b0.z); bv[3] = f16b(b0.w);
            bv[4] = f16b(b1.x); bv[5] = f16b(b1.y); bv[6] = f16b(b1.z); bv[7] = f16b(b1.w);
            __syncthreads();
            *(u16x8*)&Al[r][c8] = av;
            *(u16x8*)&Bl[r][c8] = bv;
            __syncthreads();
            f16x8 afr = *(const f16x8*)&Al[16 * wv + l15][8 * g];
#pragma unroll
            for (int ni = 0; ni < 4; ++ni) {
                f16x8 bfr = *(const f16x8*)&Bl[16 * ni + l15][8 * g];
                acc[ni] = __builtin_amdgcn_mfma_f32_16x16x32_f16(afr, bfr, acc[ni], 0, 0, 0);
            }
        }
        // epilogue: acc -> Tl (transpose) -> fragment-major coalesced stores
#pragma unroll
        for (int ni = 0; ni < 4; ++ni) {
            const int nl = 16 * ni + l15;
            const float bvs = bias[n0 + nl];
#pragma unroll
            for (int rr = 0; rr < 4; ++rr)
                Tl[nl][16 * wv + 4 * g + rr] = f16b(acc[ni][rr] + bvs);
        }
        __syncthreads();
        const int jb0 = m0 >> 5;
#pragma unroll
        for (int q = 0; q < 2; ++q) {
            const int id = tid + 256 * q;
            const int jb_l = id >> 8, rem = id & 255;
            const int c_l = rem >> 2, gf = rem & 3;
            u16x8 v = *(const u16x8*)&Tl[c_l][32 * jb_l + 8 * gf];
            *(u16x8*)&WhF[(size_t)(((jb0 + jb_l) * 256 + n0 + c_l) * 4 + gf) * 8] = v;
        }
        return;
    }
    // ---- srcdst: 16 rows x 16 k-slices + fused per-head dst max ----
    const int bs = blockIdx.x - 256;
    const int ii = tid >> 4, ki = tid & 15;
    const int i = bs * 16 + ii;
    const int KS = K >> 4;
    const int k0 = ki * KS;
    float acc[8] = {};
    for (int k = k0; k < k0 + KS; k += 4) {
        const float4 xv = *(const float4*)&X[(size_t)i * K + k];
#pragma unroll
        for (int hs = 0; hs < 8; ++hs) {
            const float4 vv = *(const float4*)&va[(size_t)hs * K + k];
            acc[hs] += xv.x * vv.x + xv.y * vv.y + xv.z * vv.z + xv.w * vv.w;
        }
    }
#pragma unroll
    for (int hs = 0; hs < 8; ++hs) red[ii][ki][hs] = acc[hs];
    __syncthreads();
    if (tid < 128) {
        const int row = tid >> 3, hs = tid & 7, h = hs >> 1;
        float sum = 0.f;
#pragma unroll
        for (int kk = 0; kk < 16; ++kk) sum += red[row][kk][hs];
        const float val = sum + vc[hs];
        const int ig = bs * 16 + row;
        if ((hs & 1) == 0) {
            srcT[h * MROWS + ig] = val;
        } else {
            dstT[h * MROWS + ig] = val;
            dred[h][row] = val;
        }
    }
    __syncthreads();
    if (tid < 4) {
        float m = -3.4e38f;
#pragma unroll
        for (int r = 0; r < 16; ++r) m = fmaxf(m, dred[tid][r]);
        const u32 b = __builtin_bit_cast(u32, m);
        const u32 key = (b & 0x80000000u) ? ~b : (b | 0x80000000u);
        atomicMax(dmu + tid, key);
    }
}

// ---------------- attention: barrier-free main loop, fragment-major B loads ----------------
// w' = mask ? exp(lrelu(s+d) - C_i) : 0 via branch select (pos ? G1*F1 : G2*F2).
template <int JT>
__global__ __launch_bounds__(512) void attn_kernel(const u16* __restrict__ WhF,
                                                   const float* __restrict__ srcT,
                                                   const float* __restrict__ dstT,
                                                   const u32* __restrict__ AbitsT,
                                                   const u32* __restrict__ dmu,
                                                   u16* __restrict__ partial,
                                                   float* __restrict__ outF) {
    constexpr int J64 = JT * 64;                    // j's per chunk
    __shared__ __align__(16) float GT[8 * J64];     // [(h*2+br)][j] f32 exps
    const int tid = threadIdx.x;
    const int lane = tid & 63, w = tid >> 6;
    const int h = w & 3, half = w >> 2;
    const int l15 = lane & 15, g = lane >> 4;
    const int i0 = blockIdx.x * 64;
    const int chunk = blockIdx.y;
    const int jbase = chunk * J64;

    // ---- prologue: G tables (once per block) ----
    for (int e = tid; e < 8 * J64; e += 512) {
        const int hb = e / J64;                     // h*2 + br
        const int j = e - hb * J64;
        const float dmhe = dmu_decode(dmu[hb >> 1]);
        const float sc = (hb & 1) ? 0.01f * LOG2E : LOG2E;
        GT[e] = __builtin_amdgcn_exp2f((dstT[(hb >> 1) * MROWS + jbase + j] - dmhe) * sc);
    }

    // ---- per-row F factors ----
    const float dmh = dmu_decode(dmu[h]);
    float negs_[2], F1_[2], F2_[2];
#pragma unroll
    for (int mi = 0; mi < 2; ++mi) {
        const float s = srcT[h * MROWS + i0 + 32 * half + 16 * mi + l15];
        const float sd = s + dmh;
        const float C = fmaxf(sd, 0.01f * sd);
        negs_[mi] = -s;
        F1_[mi] = __builtin_amdgcn_exp2f((sd - C) * LOG2E);
        F2_[mi] = __builtin_amdgcn_exp2f((0.01f * sd - C) * LOG2E);
    }
    __syncthreads();   // GT ready; no barriers after this point

    f32x4 acc[2][4] = {};
    f32x4 acc1[2] = {};
    f16x8 ones;
#pragma unroll
    for (int e = 0; e < 8; ++e) ones[e] = (f16_t)1.0f;

    for (int jt = 0; jt < JT; ++jt) {
        const int j0 = jbase + jt * 64;
        f16x8 af[2];
#pragma unroll
        for (int kj = 0; kj < 2; ++kj) {
            const int jk = j0 + 32 * kj + 8 * g;
            const float4 d0 = *(const float4*)&dstT[h * MROWS + jk];
            const float4 d1 = *(const float4*)&dstT[h * MROWS + jk + 4];
            float dv[8] = {d0.x, d0.y, d0.z, d0.w, d1.x, d1.y, d1.z, d1.w};
            const int goff = jt * 64 + 32 * kj + 8 * g;
            const float4 g10 = *(const float4*)&GT[(h * 2) * J64 + goff];
            const float4 g11 = *(const float4*)&GT[(h * 2) * J64 + goff + 4];
            const float4 g20 = *(const float4*)&GT[(h * 2 + 1) * J64 + goff];
            const float4 g21 = *(const float4*)&GT[(h * 2 + 1) * J64 + goff + 4];
            const float G1[8] = {g10.x, g10.y, g10.z, g10.w, g11.x, g11.y, g11.z, g11.w};
            const float G2[8] = {g20.x, g20.y, g20.z, g20.w, g21.x, g21.y, g21.z, g21.w};
#pragma unroll
            for (int mi = 0; mi < 2; ++mi) {
                const int irow = i0 + 32 * half + 16 * mi + l15;
                const u32 word = AbitsT[(size_t)((j0 >> 5) + kj) * MROWS + irow];
                const u32 bits = (word >> (8 * g)) & 0xffu;
                f16x8 a;
#pragma unroll
                for (int e = 0; e < 8; ++e) {
                    const bool pos = dv[e] >= negs_[mi];
                    float wv = (pos ? G1[e] : G2[e]) * (pos ? F1_[mi] : F2_[mi]);
                    wv = ((bits >> e) & 1u) ? wv : 0.f;
                    a[e] = (f16_t)wv;
                }
                af[mi] = a;
            }
            const int jb = (j0 >> 5) + kj;
#pragma unroll
            for (int ni = 0; ni < 4; ++ni) {
                const int c = h * COUT + 16 * ni + l15;
                f16x8 b = *(const f16x8*)&WhF[(size_t)(((jb << 8) + c) * 4 + g) * 8];
                acc[0][ni] = __builtin_amdgcn_mfma_f32_16x16x32_f16(af[0], b, acc[0][ni], 0, 0, 0);
                acc[1][ni] = __builtin_amdgcn_mfma_f32_16x16x32_f16(af[1], b, acc[1][ni], 0, 0, 0);
            }
            acc1[0] = __builtin_amdgcn_mfma_f32_16x16x32_f16(af[0], ones, acc1[0], 0, 0, 0);
            acc1[1] = __builtin_amdgcn_mfma_f32_16x16x32_f16(af[1], ones, acc1[1], 0, 0, 0);
        }
    }

    if (partial) {
        u16* pc = partial + (size_t)chunk * MROWS * PLD;
#pragma unroll
        for (int mi = 0; mi < 2; ++mi) {
#pragma unroll
            for (int ni = 0; ni < 4; ++ni)
#pragma unroll
                for (int rr = 0; rr < 4; ++rr) {
                    const int i = i0 + 32 * half + 16 * mi + 4 * g + rr;
                    pc[(size_t)i * PLD + h * COUT + 16 * ni + l15] = f16b(acc[mi][ni][rr]);
                }
#pragma unroll
            for (int rr = 0; rr < 4; ++rr)
                if (l15 == rr)
                    pc[(size_t)(i0 + 32 * half + 16 * mi + 4 * g + rr) * PLD + 256 + h] =
                        f16b(acc1[mi][rr]);
        }
    } else {
#pragma unroll
        for (int mi = 0; mi < 2; ++mi)
#pragma unroll
            for (int rr = 0; rr < 4; ++rr) {
                const int i = i0 + 32 * half + 16 * mi + 4 * g + rr;
                const float rs = acc1[mi][rr];
#pragma unroll
                for (int ni = 0; ni < 4; ++ni)
                    outF[(size_t)i * OHF + h * COUT + 16 * ni + l15] = acc[mi][ni][rr] / rs;
            }
    }
}

// ---------------- combine chunked f16 partials (+ optional fused classifier) ----------------
__global__ __launch_bounds__(256) void combine_kernel(const u16* __restrict__ partial,
                                                      int nchunk,
                                                      float* __restrict__ outF,
                                                      const float* __restrict__ FLw,
                                                      const float* __restrict__ FLb,
                                                      float* __restrict__ outL) {
    __shared__ float xrow[256];
    __shared__ float cred[40][4];
    const int i = blockIdx.x, c = threadIdx.x, h = c >> 6;
    float v = 0.f, rs = 0.f;
    for (int ch = 0; ch < nchunk; ++ch) {
        const u16* pc = partial + (size_t)ch * MROWS * PLD + (size_t)i * PLD;
        v += f16f(pc[c]);
        rs += f16f(pc[256 + h]);
    }
    const float r = v / rs;
    outF[(size_t)i * OHF + c] = r;
    if (!FLw) return;
    xrow[c] = r;
    __syncthreads();
    if (c < 160) {
        const int k = c >> 2, seg = c & 3;
        const float* xp = &xrow[seg * 64];
        const float* wp = &FLw[(size_t)k * OHF + seg * 64];
        float a = 0.f;
#pragma unroll
        for (int t = 0; t < 64; t += 4) {
            const float4 x4 = *(const float4*)&xp[t];
            const float4 w4 = *(const float4*)&wp[t];
            a += x4.x * w4.x + x4.y * w4.y + x4.z * w4.z + x4.w * w4.w;
        }
        cred[k][seg] = a;
    }
    __syncthreads();
    if (c < NCLS)
        outL[(size_t)i * NCLS + c] = cred[c][0] + cred[c][1] + cred[c][2] + cred[c][3] + FLb[c];
}

extern "C" void kernel_launch(void* const* d_in, const int* in_sizes, int n_in,
                              void* d_out, int out_size, void* d_ws, size_t ws_size,
                              hipStream_t stream) {
    const float* hIn = (const float*)d_in[0];
    const int*   A   = (const int*)d_in[1];
    const float* W1w = (const float*)d_in[2];
    const float* W1b = (const float*)d_in[3];
    const float* a1  = (const float*)d_in[4];
    const float* W3w = (const float*)d_in[5];
    const float* W3b = (const float*)d_in[6];
    const float* W2w = (const float*)d_in[7];
    const float* W2b = (const float*)d_in[8];
    const float* a2  = (const float*)d_in[9];
    const float* FLw = (const float*)d_in[10];
    const float* FLb = (const float*)d_in[11];
    float* outX = (float*)d_out;                     // x: (4096 x 256) fp32
    float* outL = outX + (size_t)MROWS * OHF;        // logits: (4096 x 40) fp32

    char* p = (char*)d_ws;
    auto alloc = [&](size_t bytes) { char* q = p; p += (bytes + 255) & ~(size_t)255; return q; };
    u32*   AbitsT = (u32*)alloc((size_t)MROWS * 128 * 4);
    u16*   WhF1  = (u16*)alloc((size_t)OHF * MROWS * 2);
    u16*   WhF2  = (u16*)alloc((size_t)OHF * MROWS * 2);
    float* x1f   = (float*)alloc((size_t)MROWS * OHF * 4);
    float* Cwf   = (float*)alloc((size_t)256 * 256 * 4);
    float* cbf   = (float*)alloc(256 * 4);
    float* va1   = (float*)alloc((size_t)8 * 512 * 4);
    float* vc1   = (float*)alloc(8 * 4);
    float* va2   = (float*)alloc((size_t)8 * 256 * 4);
    float* vc2   = (float*)alloc(8 * 4);
    float* srcT1 = (float*)alloc((size_t)NHEADS * MROWS * 4);
    float* dstT1 = (float*)alloc((size_t)NHEADS * MROWS * 4);
    float* srcT2 = (float*)alloc((size_t)NHEADS * MROWS * 4);
    float* dstT2 = (float*)alloc((size_t)NHEADS * MROWS * 4);
    u32*   dmu   = (u32*)alloc(8 * 4);               // [0..3]=layer1, [4..7]=layer2
    size_t fixed = (size_t)(p - (char*)d_ws);
    int nchunk = 8;
    if (fixed + (size_t)8 * MROWS * PLD * 2 > ws_size) nchunk = 4;
    u16* partial = (u16*)p;

    dim3 blk(256);
    init_kernel<<<dim3(2308), blk, 0, stream>>>(A, AbitsT, W1w, W1b, a1, W2w, W2b,
                                                W3w, W3b, a2, Cwf, cbf, va1, vc1,
                                                va2, vc2, dmu);

    auto launch_attn = [&](const u16* WhF, const float* srcT, const float* dstT,
                           const u32* dm) {
        if (nchunk == 8)
            attn_kernel<8><<<dim3(64, 8), dim3(512), 0, stream>>>(WhF, srcT, dstT, AbitsT, dm, partial, nullptr);
        else
            attn_kernel<16><<<dim3(64, 4), dim3(512), 0, stream>>>(WhF, srcT, dstT, AbitsT, dm, partial, nullptr);
    };

    // ---- layer 1 ----
    proj_kernel<<<dim3(512), blk, 0, stream>>>(hIn, W1w, W1b, 512, WhF1,
                                               va1, vc1, srcT1, dstT1, dmu);
    launch_attn(WhF1, srcT1, dstT1, dmu);
    combine_kernel<<<dim3(4096), blk, 0, stream>>>(partial, nchunk, x1f,
                                                   nullptr, nullptr, nullptr);

    // ---- layer 2 (W3∘W2 fused into Cwf; scores exact from x1f via va2) ----
    proj_kernel<<<dim3(512), blk, 0, stream>>>(x1f, Cwf, cbf, 256, WhF2,
                                               va2, vc2, srcT2, dstT2, dmu + 4);
    launch_attn(WhF2, srcT2, dstT2, dmu + 4);
    combine_kernel<<<dim3(4096), blk, 0, stream>>>(partial, nchunk, outX,
                                                   FLw, FLb, outL);
}

// Round 13
// 177.252 us; speedup vs baseline: 1.3264x; 1.0258x over previous
//
#include <hip/hip_runtime.h>
#include <hip/hip_bf16.h>

typedef _Float16 f16_t;
typedef unsigned short u16;
typedef unsigned int u32;
typedef float f32x4 __attribute__((ext_vector_type(4)));
typedef f16_t f16x8 __attribute__((ext_vector_type(8)));
typedef u16 u16x8 __attribute__((ext_vector_type(8)));
typedef u16 u16x4 __attribute__((ext_vector_type(4)));

#define MROWS 4096
#define NHEADS 4
#define COUT 64
#define OHF 256   // NHEADS*COUT
#define NCLS 40
#define LOG2E 1.4426950408889634f
#define PLD 264   // partial row length (u16): 256 acc + 4 rowsum + pad

static __device__ __forceinline__ u16 f16b(float x) {
    return __builtin_bit_cast(u16, (f16_t)x);
}
static __device__ __forceinline__ float f16f(u16 x) {
    return (float)__builtin_bit_cast(f16_t, x);
}
static __device__ __forceinline__ float dmu_decode(u32 ku) {
    const u32 fb = (ku & 0x80000000u) ? (ku ^ 0x80000000u) : ~ku;
    return __builtin_bit_cast(float, fb);
}

// ---------------- init: A->AbitsT (transposed bitmask) + prep (Cw, va1, va2, dmu) ----------------
__global__ __launch_bounds__(256) void init_kernel(const int* __restrict__ A,
                                                   u32* __restrict__ AbitsT,
                                                   const float* __restrict__ W1w,
                                                   const float* __restrict__ W1b,
                                                   const float* __restrict__ a1,
                                                   const float* __restrict__ W2w,
                                                   const float* __restrict__ W2b,
                                                   const float* __restrict__ W3w,
                                                   const float* __restrict__ W3b,
                                                   const float* __restrict__ a2,
                                                   float* __restrict__ Cwf,
                                                   float* __restrict__ cbf,
                                                   float* __restrict__ va1,
                                                   float* __restrict__ vc1,
                                                   float* __restrict__ va2,
                                                   float* __restrict__ vc2,
                                                   u32* __restrict__ dmu) {
    __shared__ u32 W[2][128];
    __shared__ float u[8][64];
    const int bx = blockIdx.x, tid = threadIdx.x;
    if (bx < 2048) {
        const int i0 = bx * 2;
        const int lane = tid & 63, wv = tid >> 6;
        for (int t = wv; t < 32; t += 4) {
            const int r = t >> 4, q = t & 15;
            const size_t base = (size_t)(i0 + r) * MROWS + q * 256 + lane;
            const int a0 = A[base];
            const int a1_ = A[base + 64];
            const int a2_ = A[base + 128];
            const int a3 = A[base + 192];
            const unsigned long long b0 = __ballot(a0 != 0);
            const unsigned long long b1 = __ballot(a1_ != 0);
            const unsigned long long b2 = __ballot(a2_ != 0);
            const unsigned long long b3 = __ballot(a3 != 0);
            if (lane == 0) {
                W[r][q * 8 + 0] = (u32)b0;
                W[r][q * 8 + 2] = (u32)b1;
                W[r][q * 8 + 4] = (u32)b2;
                W[r][q * 8 + 6] = (u32)b3;
            } else if (lane == 1) {
                W[r][q * 8 + 1] = (u32)(b0 >> 32);
                W[r][q * 8 + 3] = (u32)(b1 >> 32);
                W[r][q * 8 + 5] = (u32)(b2 >> 32);
                W[r][q * 8 + 7] = (u32)(b3 >> 32);
            }
        }
        __syncthreads();
        {
            const int jw = tid >> 1, r = tid & 1;
            AbitsT[(size_t)jw * MROWS + i0 + r] = W[r][jw];
        }
        return;
    }
    const int bid = bx - 2048;
    if (bid < 256) {
        float acc = 0.f;
        for (int t = 0; t < 64; ++t)
            acc += W2w[bid * 64 + t] * W3w[t * 256 + tid];
        Cwf[bid * 256 + tid] = acc;
        if (tid == 0) {
            float b = 0.f;
            for (int t = 0; t < 64; ++t) b += W2w[bid * 64 + t] * W3b[t];
            cbf[bid] = b + W2b[bid];
        }
    } else if (bid < 258) {
        const int k = (bid - 256) * 256 + tid;
#pragma unroll
        for (int hs = 0; hs < 8; ++hs) {
            const int h = hs >> 1, s = hs & 1;
            float acc = 0.f;
            for (int c = 0; c < COUT; ++c)
                acc += W1w[(size_t)(h * COUT + c) * 512 + k] * a1[h * 128 + s * COUT + c];
            va1[hs * 512 + k] = acc;
        }
        if (bid == 256 && tid == 0) {
            for (int hs = 0; hs < 8; ++hs) {
                const int h = hs >> 1, s = hs & 1;
                float b = 0.f;
                for (int c = 0; c < COUT; ++c) b += W1b[h * COUT + c] * a1[h * 128 + s * COUT + c];
                vc1[hs] = b;
            }
        }
    } else if (bid == 258) {
#pragma unroll
        for (int e = tid * 2; e < tid * 2 + 2; ++e) {
            const int hs = e >> 6, t = e & 63;
            const int h = hs >> 1, s = hs & 1;
            float acc = 0.f;
            for (int c = 0; c < COUT; ++c)
                acc += W2w[(size_t)(h * COUT + c) * 64 + t] * a2[h * 128 + s * COUT + c];
            u[hs][t] = acc;
        }
        __syncthreads();
#pragma unroll
        for (int hs = 0; hs < 8; ++hs) {
            float acc = 0.f;
            for (int t = 0; t < 64; ++t) acc += u[hs][t] * W3w[t * 256 + tid];
            va2[hs * 256 + tid] = acc;
        }
        if (tid == 0) {
            for (int hs = 0; hs < 8; ++hs) {
                const int h = hs >> 1, s = hs & 1;
                float b = 0.f;
                for (int t = 0; t < 64; ++t) b += u[hs][t] * W3b[t];
                for (int c = 0; c < COUT; ++c) b += W2b[h * COUT + c] * a2[h * 128 + s * COUT + c];
                vc2[hs] = b;
            }
        }
    } else {
        if (tid < 8) dmu[tid] = 0u;   // monotone-mapped -inf
    }
}

// ---------------- proj: fused {gemm16 -> fragment-major WhF} + {srcdst} ----------------
// WhF layout: chunk (jb, c, g) = 8 f16 of Wh^T[c][jb*32 + 8g .. +8] at u16 index ((jb*256+c)*4+g)*8
__global__ __launch_bounds__(256) void proj_kernel(const float* __restrict__ X,
                                                   const float* __restrict__ Bm,
                                                   const float* __restrict__ bias,
                                                   int K,
                                                   u16* __restrict__ WhF,
                                                   const float* __restrict__ va,
                                                   const float* __restrict__ vc,
                                                   float* __restrict__ srcT,
                                                   float* __restrict__ dstT,
                                                   u32* __restrict__ dmu) {
    __shared__ u16 Al[64][40];
    __shared__ u16 Bl[64][40];
    __shared__ u16 Tl[64][72];        // [n-local][m-local], padded: b128-aligned rows
    __shared__ float red[16][16][9];
    __shared__ float dred[4][16];
    const int tid = threadIdx.x;
    if (blockIdx.x < 256) {
        // ---- GEMM: fragment-major output ----
        const int lane = tid & 63, wv = tid >> 6;
        const int l15 = lane & 15, g = lane >> 4;
        const int m0 = (blockIdx.x & 63) * 64, n0 = (blockIdx.x >> 6) * 64;
        const int r = tid >> 2, c8 = (tid & 3) * 8;
        f32x4 acc[4] = {};
        for (int k0 = 0; k0 < K; k0 += 32) {
            const float4 a0 = *(const float4*)&X[(size_t)(m0 + r) * K + k0 + c8];
            const float4 a1 = *(const float4*)&X[(size_t)(m0 + r) * K + k0 + c8 + 4];
            const float4 b0 = *(const float4*)&Bm[(size_t)(n0 + r) * K + k0 + c8];
            const float4 b1 = *(const float4*)&Bm[(size_t)(n0 + r) * K + k0 + c8 + 4];
            u16x8 av, bv;
            av[0] = f16b(a0.x); av[1] = f16b(a0.y); av[2] = f16b(a0.z); av[3] = f16b(a0.w);
            av[4] = f16b(a1.x); av[5] = f16b(a1.y); av[6] = f16b(a1.z); av[7] = f16b(a1.w);
            bv[0] = f16b(b0.x); bv[1] = f16b(b0.y); bv[2] = f16b(b0.z); bv[3] = f16b(b0.w);
            bv[4] = f16b(b1.x); bv[5] = f16b(b1.y); bv[6] = f16b(b1.z); bv[7] = f16b(b1.w);
            __syncthreads();
            *(u16x8*)&Al[r][c8] = av;
            *(u16x8*)&Bl[r][c8] = bv;
            __syncthreads();
            f16x8 afr = *(const f16x8*)&Al[16 * wv + l15][8 * g];
#pragma unroll
            for (int ni = 0; ni < 4; ++ni) {
                f16x8 bfr = *(const f16x8*)&Bl[16 * ni + l15][8 * g];
                acc[ni] = __builtin_amdgcn_mfma_f32_16x16x32_f16(afr, bfr, acc[ni], 0, 0, 0);
            }
        }
        // epilogue: acc -> Tl (transpose) -> fragment-major coalesced stores
#pragma unroll
        for (int ni = 0; ni < 4; ++ni) {
            const int nl = 16 * ni + l15;
            const float bvs = bias[n0 + nl];
#pragma unroll
            for (int rr = 0; rr < 4; ++rr)
                Tl[nl][16 * wv + 4 * g + rr] = f16b(acc[ni][rr] + bvs);
        }
        __syncthreads();
        const int jb0 = m0 >> 5;
#pragma unroll
        for (int q = 0; q < 2; ++q) {
            const int id = tid + 256 * q;
            const int jb_l = id >> 8, rem = id & 255;
            const int c_l = rem >> 2, gf = rem & 3;
            u16x8 v = *(const u16x8*)&Tl[c_l][32 * jb_l + 8 * gf];
            *(u16x8*)&WhF[(size_t)(((jb0 + jb_l) * 256 + n0 + c_l) * 4 + gf) * 8] = v;
        }
        return;
    }
    // ---- srcdst: 16 rows x 16 k-slices + fused per-head dst max ----
    const int bs = blockIdx.x - 256;
    const int ii = tid >> 4, ki = tid & 15;
    const int i = bs * 16 + ii;
    const int KS = K >> 4;
    const int k0 = ki * KS;
    float acc[8] = {};
    for (int k = k0; k < k0 + KS; k += 4) {
        const float4 xv = *(const float4*)&X[(size_t)i * K + k];
#pragma unroll
        for (int hs = 0; hs < 8; ++hs) {
            const float4 vv = *(const float4*)&va[(size_t)hs * K + k];
            acc[hs] += xv.x * vv.x + xv.y * vv.y + xv.z * vv.z + xv.w * vv.w;
        }
    }
#pragma unroll
    for (int hs = 0; hs < 8; ++hs) red[ii][ki][hs] = acc[hs];
    __syncthreads();
    if (tid < 128) {
        const int row = tid >> 3, hs = tid & 7, h = hs >> 1;
        float sum = 0.f;
#pragma unroll
        for (int kk = 0; kk < 16; ++kk) sum += red[row][kk][hs];
        const float val = sum + vc[hs];
        const int ig = bs * 16 + row;
        if ((hs & 1) == 0) {
            srcT[h * MROWS + ig] = val;
        } else {
            dstT[h * MROWS + ig] = val;
            dred[h][row] = val;
        }
    }
    __syncthreads();
    if (tid < 4) {
        float m = -3.4e38f;
#pragma unroll
        for (int r = 0; r < 16; ++r) m = fmaxf(m, dred[tid][r]);
        const u32 b = __builtin_bit_cast(u32, m);
        const u32 key = (b & 0x80000000u) ? ~b : (b | 0x80000000u);
        atomicMax(dmu + tid, key);
    }
}

// ---------------- attention: 32-row blocks, wave=(h,mi), f32 max-identity scoring ----------------
// w' = mask ? max(F1_i*G1_j, F2_i*G2_j) : 0   (= exp(lrelu(s+d) - C_i); all factors <= 1)
template <int JT>
__global__ __launch_bounds__(512) void attn_kernel(const u16* __restrict__ WhF,
                                                   const float* __restrict__ srcT,
                                                   const float* __restrict__ dstT,
                                                   const u32* __restrict__ AbitsT,
                                                   const u32* __restrict__ dmu,
                                                   u16* __restrict__ partial,
                                                   float* __restrict__ outF) {
    constexpr int J64 = JT * 64;                    // j's per chunk
    __shared__ __align__(16) float GT[8 * J64];     // [(h*2+br)][j] f32 exps
    const int tid = threadIdx.x;
    const int lane = tid & 63, w = tid >> 6;
    const int h = w & 3, mi = w >> 2;               // wave = (head, mi-group)
    const int l15 = lane & 15, g = lane >> 4;
    const int i0 = blockIdx.x * 32;
    const int chunk = blockIdx.y;
    const int jbase = chunk * J64;

    // ---- prologue: G tables (once per block) ----
    for (int e = tid; e < 8 * J64; e += 512) {
        const int hb = e / J64;                     // h*2 + br
        const int j = e - hb * J64;
        const float dmhe = dmu_decode(dmu[hb >> 1]);
        const float sc = (hb & 1) ? 0.01f * LOG2E : LOG2E;
        GT[e] = __builtin_amdgcn_exp2f((dstT[(hb >> 1) * MROWS + jbase + j] - dmhe) * sc);
    }

    // ---- per-row F factors ----
    const float dmh = dmu_decode(dmu[h]);
    const float s = srcT[h * MROWS + i0 + 16 * mi + l15];
    const float sd = s + dmh;
    const float C = fmaxf(sd, 0.01f * sd);
    const float F1 = __builtin_amdgcn_exp2f((sd - C) * LOG2E);
    const float F2 = __builtin_amdgcn_exp2f((0.01f * sd - C) * LOG2E);
    __syncthreads();   // GT ready; no barriers after this point

    f32x4 acc[4] = {};
    f32x4 acc1 = {};
    f16x8 ones;
#pragma unroll
    for (int e = 0; e < 8; ++e) ones[e] = (f16_t)1.0f;
    const int irow = i0 + 16 * mi + l15;

    for (int jt = 0; jt < JT; ++jt) {
        const int j0 = jbase + jt * 64;
#pragma unroll
        for (int kj = 0; kj < 2; ++kj) {
            const int goff = jt * 64 + 32 * kj + 8 * g;
            const float4 g10 = *(const float4*)&GT[(h * 2) * J64 + goff];
            const float4 g11 = *(const float4*)&GT[(h * 2) * J64 + goff + 4];
            const float4 g20 = *(const float4*)&GT[(h * 2 + 1) * J64 + goff];
            const float4 g21 = *(const float4*)&GT[(h * 2 + 1) * J64 + goff + 4];
            const float G1[8] = {g10.x, g10.y, g10.z, g10.w, g11.x, g11.y, g11.z, g11.w};
            const float G2[8] = {g20.x, g20.y, g20.z, g20.w, g21.x, g21.y, g21.z, g21.w};
            const int jb = (j0 >> 5) + kj;
            const u32 word = AbitsT[(size_t)jb * MROWS + irow];
            const u32 bits = (word >> (8 * g)) & 0xffu;
            f16x8 a;
#pragma unroll
            for (int e = 0; e < 8; ++e) {
                float wv = fmaxf(G1[e] * F1, G2[e] * F2);
                wv = ((bits >> e) & 1u) ? wv : 0.f;
                a[e] = (f16_t)wv;
            }
#pragma unroll
            for (int ni = 0; ni < 4; ++ni) {
                const int c = h * COUT + 16 * ni + l15;
                f16x8 b = *(const f16x8*)&WhF[(size_t)(((jb << 8) + c) * 4 + g) * 8];
                acc[ni] = __builtin_amdgcn_mfma_f32_16x16x32_f16(a, b, acc[ni], 0, 0, 0);
            }
            acc1 = __builtin_amdgcn_mfma_f32_16x16x32_f16(a, ones, acc1, 0, 0, 0);
        }
    }

    if (partial) {
        u16* pc = partial + (size_t)chunk * MROWS * PLD;
#pragma unroll
        for (int ni = 0; ni < 4; ++ni)
#pragma unroll
            for (int rr = 0; rr < 4; ++rr) {
                const int i = i0 + 16 * mi + 4 * g + rr;
                pc[(size_t)i * PLD + h * COUT + 16 * ni + l15] = f16b(acc[ni][rr]);
            }
#pragma unroll
        for (int rr = 0; rr < 4; ++rr)
            if (l15 == rr)
                pc[(size_t)(i0 + 16 * mi + 4 * g + rr) * PLD + 256 + h] = f16b(acc1[rr]);
    } else {
#pragma unroll
        for (int rr = 0; rr < 4; ++rr) {
            const int i = i0 + 16 * mi + 4 * g + rr;
            const float rs = acc1[rr];
#pragma unroll
            for (int ni = 0; ni < 4; ++ni)
                outF[(size_t)i * OHF + h * COUT + 16 * ni + l15] = acc[ni][rr] / rs;
        }
    }
}

// ---------------- combine chunked f16 partials (+ optional fused classifier) ----------------
__global__ __launch_bounds__(256) void combine_kernel(const u16* __restrict__ partial,
                                                      int nchunk,
                                                      float* __restrict__ outF,
                                                      const float* __restrict__ FLw,
                                                      const float* __restrict__ FLb,
                                                      float* __restrict__ outL) {
    __shared__ float xrow[256];
    __shared__ float cred[40][4];
    const int i = blockIdx.x, c = threadIdx.x, h = c >> 6;
    float v = 0.f, rs = 0.f;
    for (int ch = 0; ch < nchunk; ++ch) {
        const u16* pc = partial + (size_t)ch * MROWS * PLD + (size_t)i * PLD;
        v += f16f(pc[c]);
        rs += f16f(pc[256 + h]);
    }
    const float r = v / rs;
    outF[(size_t)i * OHF + c] = r;
    if (!FLw) return;
    xrow[c] = r;
    __syncthreads();
    if (c < 160) {
        const int k = c >> 2, seg = c & 3;
        const float* xp = &xrow[seg * 64];
        const float* wp = &FLw[(size_t)k * OHF + seg * 64];
        float a = 0.f;
#pragma unroll
        for (int t = 0; t < 64; t += 4) {
            const float4 x4 = *(const float4*)&xp[t];
            const float4 w4 = *(const float4*)&wp[t];
            a += x4.x * w4.x + x4.y * w4.y + x4.z * w4.z + x4.w * w4.w;
        }
        cred[k][seg] = a;
    }
    __syncthreads();
    if (c < NCLS)
        outL[(size_t)i * NCLS + c] = cred[c][0] + cred[c][1] + cred[c][2] + cred[c][3] + FLb[c];
}

extern "C" void kernel_launch(void* const* d_in, const int* in_sizes, int n_in,
                              void* d_out, int out_size, void* d_ws, size_t ws_size,
                              hipStream_t stream) {
    const float* hIn = (const float*)d_in[0];
    const int*   A   = (const int*)d_in[1];
    const float* W1w = (const float*)d_in[2];
    const float* W1b = (const float*)d_in[3];
    const float* a1  = (const float*)d_in[4];
    const float* W3w = (const float*)d_in[5];
    const float* W3b = (const float*)d_in[6];
    const float* W2w = (const float*)d_in[7];
    const float* W2b = (const float*)d_in[8];
    const float* a2  = (const float*)d_in[9];
    const float* FLw = (const float*)d_in[10];
    const float* FLb = (const float*)d_in[11];
    float* outX = (float*)d_out;                     // x: (4096 x 256) fp32
    float* outL = outX + (size_t)MROWS * OHF;        // logits: (4096 x 40) fp32

    char* p = (char*)d_ws;
    auto alloc = [&](size_t bytes) { char* q = p; p += (bytes + 255) & ~(size_t)255; return q; };
    u32*   AbitsT = (u32*)alloc((size_t)MROWS * 128 * 4);
    u16*   WhF1  = (u16*)alloc((size_t)OHF * MROWS * 2);
    u16*   WhF2  = (u16*)alloc((size_t)OHF * MROWS * 2);
    float* x1f   = (float*)alloc((size_t)MROWS * OHF * 4);
    float* Cwf   = (float*)alloc((size_t)256 * 256 * 4);
    float* cbf   = (float*)alloc(256 * 4);
    float* va1   = (float*)alloc((size_t)8 * 512 * 4);
    float* vc1   = (float*)alloc(8 * 4);
    float* va2   = (float*)alloc((size_t)8 * 256 * 4);
    float* vc2   = (float*)alloc(8 * 4);
    float* srcT1 = (float*)alloc((size_t)NHEADS * MROWS * 4);
    float* dstT1 = (float*)alloc((size_t)NHEADS * MROWS * 4);
    float* srcT2 = (float*)alloc((size_t)NHEADS * MROWS * 4);
    float* dstT2 = (float*)alloc((size_t)NHEADS * MROWS * 4);
    u32*   dmu   = (u32*)alloc(8 * 4);               // [0..3]=layer1, [4..7]=layer2
    size_t fixed = (size_t)(p - (char*)d_ws);
    int nchunk = 8;
    if (fixed + (size_t)8 * MROWS * PLD * 2 > ws_size) nchunk = 4;
    u16* partial = (u16*)p;

    dim3 blk(256);
    init_kernel<<<dim3(2308), blk, 0, stream>>>(A, AbitsT, W1w, W1b, a1, W2w, W2b,
                                                W3w, W3b, a2, Cwf, cbf, va1, vc1,
                                                va2, vc2, dmu);

    auto launch_attn = [&](const u16* WhF, const float* srcT, const float* dstT,
                           const u32* dm) {
        if (nchunk == 8)
            attn_kernel<8><<<dim3(128, 8), dim3(512), 0, stream>>>(WhF, srcT, dstT, AbitsT, dm, partial, nullptr);
        else
            attn_kernel<16><<<dim3(128, 4), dim3(512), 0, stream>>>(WhF, srcT, dstT, AbitsT, dm, partial, nullptr);
    };

    // ---- layer 1 ----
    proj_kernel<<<dim3(512), blk, 0, stream>>>(hIn, W1w, W1b, 512, WhF1,
                                               va1, vc1, srcT1, dstT1, dmu);
    launch_attn(WhF1, srcT1, dstT1, dmu);
    combine_kernel<<<dim3(4096), blk, 0, stream>>>(partial, nchunk, x1f,
                                                   nullptr, nullptr, nullptr);

    // ---- layer 2 (W3∘W2 fused into Cwf; scores exact from x1f via va2) ----
    proj_kernel<<<dim3(512), blk, 0, stream>>>(x1f, Cwf, cbf, 256, WhF2,
                                               va2, vc2, srcT2, dstT2, dmu + 4);
    launch_attn(WhF2, srcT2, dstT2, dmu + 4);
    combine_kernel<<<dim3(4096), blk, 0, stream>>>(partial, nchunk, outX,
                                                   FLw, FLb, outL);
}

// Round 14
// 175.924 us; speedup vs baseline: 1.3364x; 1.0075x over previous
//
#include <hip/hip_runtime.h>
#include <hip/hip_bf16.h>

typedef _Float16 f16_t;
typedef unsigned short u16;
typedef unsigned int u32;
typedef float f32x4 __attribute__((ext_vector_type(4)));
typedef f16_t f16x8 __attribute__((ext_vector_type(8)));
typedef u16 u16x8 __attribute__((ext_vector_type(8)));
typedef u16 u16x4 __attribute__((ext_vector_type(4)));

#define MROWS 4096
#define NHEADS 4
#define COUT 64
#define OHF 256   // NHEADS*COUT
#define NCLS 40
#define LOG2E 1.4426950408889634f
#define PLD 264   // partial row length (u16): 256 acc + 4 rowsum + pad

static __device__ __forceinline__ u16 f16b(float x) {
    return __builtin_bit_cast(u16, (f16_t)x);
}
static __device__ __forceinline__ float f16f(u16 x) {
    return (float)__builtin_bit_cast(f16_t, x);
}
static __device__ __forceinline__ float dmu_decode(u32 ku) {
    const u32 fb = (ku & 0x80000000u) ? (ku ^ 0x80000000u) : ~ku;
    return __builtin_bit_cast(float, fb);
}

// ---------------- init: A->AbitsT (transposed bitmask) + prep (Cw, va1, va2, dmu) ----------------
__global__ __launch_bounds__(256) void init_kernel(const int* __restrict__ A,
                                                   u32* __restrict__ AbitsT,
                                                   const float* __restrict__ W1w,
                                                   const float* __restrict__ W1b,
                                                   const float* __restrict__ a1,
                                                   const float* __restrict__ W2w,
                                                   const float* __restrict__ W2b,
                                                   const float* __restrict__ W3w,
                                                   const float* __restrict__ W3b,
                                                   const float* __restrict__ a2,
                                                   float* __restrict__ Cwf,
                                                   float* __restrict__ cbf,
                                                   float* __restrict__ va1,
                                                   float* __restrict__ vc1,
                                                   float* __restrict__ va2,
                                                   float* __restrict__ vc2,
                                                   u32* __restrict__ dmu) {
    __shared__ u32 W[2][128];
    __shared__ float u[8][64];
    const int bx = blockIdx.x, tid = threadIdx.x;
    if (bx < 2048) {
        const int i0 = bx * 2;
        const int lane = tid & 63, wv = tid >> 6;
        for (int t = wv; t < 32; t += 4) {
            const int r = t >> 4, q = t & 15;
            const size_t base = (size_t)(i0 + r) * MROWS + q * 256 + lane;
            const int a0 = A[base];
            const int a1_ = A[base + 64];
            const int a2_ = A[base + 128];
            const int a3 = A[base + 192];
            const unsigned long long b0 = __ballot(a0 != 0);
            const unsigned long long b1 = __ballot(a1_ != 0);
            const unsigned long long b2 = __ballot(a2_ != 0);
            const unsigned long long b3 = __ballot(a3 != 0);
            if (lane == 0) {
                W[r][q * 8 + 0] = (u32)b0;
                W[r][q * 8 + 2] = (u32)b1;
                W[r][q * 8 + 4] = (u32)b2;
                W[r][q * 8 + 6] = (u32)b3;
            } else if (lane == 1) {
                W[r][q * 8 + 1] = (u32)(b0 >> 32);
                W[r][q * 8 + 3] = (u32)(b1 >> 32);
                W[r][q * 8 + 5] = (u32)(b2 >> 32);
                W[r][q * 8 + 7] = (u32)(b3 >> 32);
            }
        }
        __syncthreads();
        {
            const int jw = tid >> 1, r = tid & 1;
            AbitsT[(size_t)jw * MROWS + i0 + r] = W[r][jw];
        }
        return;
    }
    const int bid = bx - 2048;
    if (bid < 256) {
        float acc = 0.f;
        for (int t = 0; t < 64; ++t)
            acc += W2w[bid * 64 + t] * W3w[t * 256 + tid];
        Cwf[bid * 256 + tid] = acc;
        if (tid == 0) {
            float b = 0.f;
            for (int t = 0; t < 64; ++t) b += W2w[bid * 64 + t] * W3b[t];
            cbf[bid] = b + W2b[bid];
        }
    } else if (bid < 258) {
        const int k = (bid - 256) * 256 + tid;
#pragma unroll
        for (int hs = 0; hs < 8; ++hs) {
            const int h = hs >> 1, s = hs & 1;
            float acc = 0.f;
            for (int c = 0; c < COUT; ++c)
                acc += W1w[(size_t)(h * COUT + c) * 512 + k] * a1[h * 128 + s * COUT + c];
            va1[hs * 512 + k] = acc;
        }
        if (bid == 256 && tid == 0) {
            for (int hs = 0; hs < 8; ++hs) {
                const int h = hs >> 1, s = hs & 1;
                float b = 0.f;
                for (int c = 0; c < COUT; ++c) b += W1b[h * COUT + c] * a1[h * 128 + s * COUT + c];
                vc1[hs] = b;
            }
        }
    } else if (bid == 258) {
#pragma unroll
        for (int e = tid * 2; e < tid * 2 + 2; ++e) {
            const int hs = e >> 6, t = e & 63;
            const int h = hs >> 1, s = hs & 1;
            float acc = 0.f;
            for (int c = 0; c < COUT; ++c)
                acc += W2w[(size_t)(h * COUT + c) * 64 + t] * a2[h * 128 + s * COUT + c];
            u[hs][t] = acc;
        }
        __syncthreads();
#pragma unroll
        for (int hs = 0; hs < 8; ++hs) {
            float acc = 0.f;
            for (int t = 0; t < 64; ++t) acc += u[hs][t] * W3w[t * 256 + tid];
            va2[hs * 256 + tid] = acc;
        }
        if (tid == 0) {
            for (int hs = 0; hs < 8; ++hs) {
                const int h = hs >> 1, s = hs & 1;
                float b = 0.f;
                for (int t = 0; t < 64; ++t) b += u[hs][t] * W3b[t];
                for (int c = 0; c < COUT; ++c) b += W2b[h * COUT + c] * a2[h * 128 + s * COUT + c];
                vc2[hs] = b;
            }
        }
    } else {
        if (tid < 8) dmu[tid] = 0u;   // monotone-mapped -inf
    }
}

// ---------------- proj: fused {gemm16 -> fragment-major WhF} + {srcdst} ----------------
// WhF layout: chunk (jb, c, g) = 8 f16 of Wh^T[c][jb*32 + 8g .. +8] at u16 index ((jb*256+c)*4+g)*8
__global__ __launch_bounds__(256) void proj_kernel(const float* __restrict__ X,
                                                   const float* __restrict__ Bm,
                                                   const float* __restrict__ bias,
                                                   int K,
                                                   u16* __restrict__ WhF,
                                                   const float* __restrict__ va,
                                                   const float* __restrict__ vc,
                                                   float* __restrict__ srcT,
                                                   float* __restrict__ dstT,
                                                   u32* __restrict__ dmu) {
    __shared__ u16 Al[64][40];
    __shared__ u16 Bl[64][40];
    __shared__ u16 Tl[64][72];        // [n-local][m-local], padded: b128-aligned rows
    __shared__ float red[16][16][9];
    __shared__ float dred[4][16];
    const int tid = threadIdx.x;
    if (blockIdx.x < 256) {
        // ---- GEMM: fragment-major output ----
        const int lane = tid & 63, wv = tid >> 6;
        const int l15 = lane & 15, g = lane >> 4;
        const int m0 = (blockIdx.x & 63) * 64, n0 = (blockIdx.x >> 6) * 64;
        const int r = tid >> 2, c8 = (tid & 3) * 8;
        f32x4 acc[4] = {};
        for (int k0 = 0; k0 < K; k0 += 32) {
            const float4 a0 = *(const float4*)&X[(size_t)(m0 + r) * K + k0 + c8];
            const float4 a1 = *(const float4*)&X[(size_t)(m0 + r) * K + k0 + c8 + 4];
            const float4 b0 = *(const float4*)&Bm[(size_t)(n0 + r) * K + k0 + c8];
            const float4 b1 = *(const float4*)&Bm[(size_t)(n0 + r) * K + k0 + c8 + 4];
            u16x8 av, bv;
            av[0] = f16b(a0.x); av[1] = f16b(a0.y); av[2] = f16b(a0.z); av[3] = f16b(a0.w);
            av[4] = f16b(a1.x); av[5] = f16b(a1.y); av[6] = f16b(a1.z); av[7] = f16b(a1.w);
            bv[0] = f16b(b0.x); bv[1] = f16b(b0.y); bv[2] = f16b(b0.z); bv[3] = f16b(b0.w);
            bv[4] = f16b(b1.x); bv[5] = f16b(b1.y); bv[6] = f16b(b1.z); bv[7] = f16b(b1.w);
            __syncthreads();
            *(u16x8*)&Al[r][c8] = av;
            *(u16x8*)&Bl[r][c8] = bv;
            __syncthreads();
            f16x8 afr = *(const f16x8*)&Al[16 * wv + l15][8 * g];
#pragma unroll
            for (int ni = 0; ni < 4; ++ni) {
                f16x8 bfr = *(const f16x8*)&Bl[16 * ni + l15][8 * g];
                acc[ni] = __builtin_amdgcn_mfma_f32_16x16x32_f16(afr, bfr, acc[ni], 0, 0, 0);
            }
        }
        // epilogue: acc -> Tl (transpose) -> fragment-major coalesced stores
#pragma unroll
        for (int ni = 0; ni < 4; ++ni) {
            const int nl = 16 * ni + l15;
            const float bvs = bias[n0 + nl];
#pragma unroll
            for (int rr = 0; rr < 4; ++rr)
                Tl[nl][16 * wv + 4 * g + rr] = f16b(acc[ni][rr] + bvs);
        }
        __syncthreads();
        const int jb0 = m0 >> 5;
#pragma unroll
        for (int q = 0; q < 2; ++q) {
            const int id = tid + 256 * q;
            const int jb_l = id >> 8, rem = id & 255;
            const int c_l = rem >> 2, gf = rem & 3;
            u16x8 v = *(const u16x8*)&Tl[c_l][32 * jb_l + 8 * gf];
            *(u16x8*)&WhF[(size_t)(((jb0 + jb_l) * 256 + n0 + c_l) * 4 + gf) * 8] = v;
        }
        return;
    }
    // ---- srcdst: 16 rows x 16 k-slices + fused per-head dst max ----
    const int bs = blockIdx.x - 256;
    const int ii = tid >> 4, ki = tid & 15;
    const int i = bs * 16 + ii;
    const int KS = K >> 4;
    const int k0 = ki * KS;
    float acc[8] = {};
    for (int k = k0; k < k0 + KS; k += 4) {
        const float4 xv = *(const float4*)&X[(size_t)i * K + k];
#pragma unroll
        for (int hs = 0; hs < 8; ++hs) {
            const float4 vv = *(const float4*)&va[(size_t)hs * K + k];
            acc[hs] += xv.x * vv.x + xv.y * vv.y + xv.z * vv.z + xv.w * vv.w;
        }
    }
#pragma unroll
    for (int hs = 0; hs < 8; ++hs) red[ii][ki][hs] = acc[hs];
    __syncthreads();
    if (tid < 128) {
        const int row = tid >> 3, hs = tid & 7, h = hs >> 1;
        float sum = 0.f;
#pragma unroll
        for (int kk = 0; kk < 16; ++kk) sum += red[row][kk][hs];
        const float val = sum + vc[hs];
        const int ig = bs * 16 + row;
        if ((hs & 1) == 0) {
            srcT[h * MROWS + ig] = val;
        } else {
            dstT[h * MROWS + ig] = val;
            dred[h][row] = val;
        }
    }
    __syncthreads();
    if (tid < 4) {
        float m = -3.4e38f;
#pragma unroll
        for (int r = 0; r < 16; ++r) m = fmaxf(m, dred[tid][r]);
        const u32 b = __builtin_bit_cast(u32, m);
        const u32 key = (b & 0x80000000u) ? ~b : (b | 0x80000000u);
        atomicMax(dmu + tid, key);
    }
}

// ---------------- attention: pipelined (1-step register prefetch), wave=(h,mi), setprio ----------------
// w' = mask ? max(F1_i*G1_j, F2_i*G2_j) : 0   (= exp(lrelu(s+d) - C_i); all factors <= 1)
template <int JT>
__global__ __launch_bounds__(512, 4) void attn_kernel(const u16* __restrict__ WhF,
                                                      const float* __restrict__ srcT,
                                                      const float* __restrict__ dstT,
                                                      const u32* __restrict__ AbitsT,
                                                      const u32* __restrict__ dmu,
                                                      u16* __restrict__ partial,
                                                      float* __restrict__ outF) {
    constexpr int J64 = JT * 64;                    // j's per chunk
    constexpr int NSTEP = 2 * JT;                   // 32-j steps
    __shared__ __align__(16) float GT[8 * J64];     // [(h*2+br)][j] f32 exps
    const int tid = threadIdx.x;
    const int lane = tid & 63, w = tid >> 6;
    const int h = w & 3, mi = w >> 2;               // wave = (head, mi-group)
    const int l15 = lane & 15, g = lane >> 4;
    const int i0 = blockIdx.x * 32;
    const int chunk = blockIdx.y;
    const int jbase = chunk * J64;

    // ---- prologue: G tables (once per block) ----
    for (int e = tid; e < 8 * J64; e += 512) {
        const int hb = e / J64;                     // h*2 + br
        const int j = e - hb * J64;
        const float dmhe = dmu_decode(dmu[hb >> 1]);
        const float sc = (hb & 1) ? 0.01f * LOG2E : LOG2E;
        GT[e] = __builtin_amdgcn_exp2f((dstT[(hb >> 1) * MROWS + jbase + j] - dmhe) * sc);
    }

    // ---- per-row F factors ----
    const float dmh = dmu_decode(dmu[h]);
    const float s = srcT[h * MROWS + i0 + 16 * mi + l15];
    const float sd = s + dmh;
    const float C = fmaxf(sd, 0.01f * sd);
    const float F1 = __builtin_amdgcn_exp2f((sd - C) * LOG2E);
    const float F2 = __builtin_amdgcn_exp2f((0.01f * sd - C) * LOG2E);
    __syncthreads();   // GT ready; no barriers after this point

    f32x4 acc[4] = {};
    f32x4 acc1 = {};
    f16x8 ones;
#pragma unroll
    for (int e = 0; e < 8; ++e) ones[e] = (f16_t)1.0f;
    const int irow = i0 + 16 * mi + l15;
    const int jb0 = jbase >> 5;
    const int cb = h * COUT + l15;                  // c for ni: cb + 16*ni

    // ---- software pipeline: prefetch step 0 ----
    u32 curW = AbitsT[(size_t)jb0 * MROWS + irow];
    f16x8 cB0 = *(const f16x8*)&WhF[(size_t)((((jb0) << 8) + cb) * 4 + g) * 8];
    f16x8 cB1 = *(const f16x8*)&WhF[(size_t)((((jb0) << 8) + cb + 16) * 4 + g) * 8];
    f16x8 cB2 = *(const f16x8*)&WhF[(size_t)((((jb0) << 8) + cb + 32) * 4 + g) * 8];
    f16x8 cB3 = *(const f16x8*)&WhF[(size_t)((((jb0) << 8) + cb + 48) * 4 + g) * 8];

#pragma unroll
    for (int t = 0; t < NSTEP; ++t) {
        // prefetch step t+1 (registers; renamed by unroll, no copies at -O3)
        u32 nW = 0;
        f16x8 nB0 = {}, nB1 = {}, nB2 = {}, nB3 = {};
        if (t + 1 < NSTEP) {
            const int jb = jb0 + t + 1;
            nW = AbitsT[(size_t)jb * MROWS + irow];
            nB0 = *(const f16x8*)&WhF[(size_t)(((jb << 8) + cb) * 4 + g) * 8];
            nB1 = *(const f16x8*)&WhF[(size_t)(((jb << 8) + cb + 16) * 4 + g) * 8];
            nB2 = *(const f16x8*)&WhF[(size_t)(((jb << 8) + cb + 32) * 4 + g) * 8];
            nB3 = *(const f16x8*)&WhF[(size_t)(((jb << 8) + cb + 48) * 4 + g) * 8];
        }
        // scores for step t (GT in LDS, mask in register)
        const int goff = t * 32 + 8 * g;
        const float4 g10 = *(const float4*)&GT[(h * 2) * J64 + goff];
        const float4 g11 = *(const float4*)&GT[(h * 2) * J64 + goff + 4];
        const float4 g20 = *(const float4*)&GT[(h * 2 + 1) * J64 + goff];
        const float4 g21 = *(const float4*)&GT[(h * 2 + 1) * J64 + goff + 4];
        const float G1[8] = {g10.x, g10.y, g10.z, g10.w, g11.x, g11.y, g11.z, g11.w};
        const float G2[8] = {g20.x, g20.y, g20.z, g20.w, g21.x, g21.y, g21.z, g21.w};
        const u32 bits = (curW >> (8 * g)) & 0xffu;
        f16x8 a;
#pragma unroll
        for (int e = 0; e < 8; ++e) {
            float wv = fmaxf(G1[e] * F1, G2[e] * F2);
            wv = ((bits >> e) & 1u) ? wv : 0.f;
            a[e] = (f16_t)wv;
        }
        __builtin_amdgcn_s_setprio(1);
        acc[0] = __builtin_amdgcn_mfma_f32_16x16x32_f16(a, cB0, acc[0], 0, 0, 0);
        acc[1] = __builtin_amdgcn_mfma_f32_16x16x32_f16(a, cB1, acc[1], 0, 0, 0);
        acc[2] = __builtin_amdgcn_mfma_f32_16x16x32_f16(a, cB2, acc[2], 0, 0, 0);
        acc[3] = __builtin_amdgcn_mfma_f32_16x16x32_f16(a, cB3, acc[3], 0, 0, 0);
        acc1 = __builtin_amdgcn_mfma_f32_16x16x32_f16(a, ones, acc1, 0, 0, 0);
        __builtin_amdgcn_s_setprio(0);
        curW = nW;
        cB0 = nB0; cB1 = nB1; cB2 = nB2; cB3 = nB3;
    }

    if (partial) {
        u16* pc = partial + (size_t)chunk * MROWS * PLD;
#pragma unroll
        for (int ni = 0; ni < 4; ++ni)
#pragma unroll
            for (int rr = 0; rr < 4; ++rr) {
                const int i = i0 + 16 * mi + 4 * g + rr;
                pc[(size_t)i * PLD + h * COUT + 16 * ni + l15] = f16b(acc[ni][rr]);
            }
#pragma unroll
        for (int rr = 0; rr < 4; ++rr)
            if (l15 == rr)
                pc[(size_t)(i0 + 16 * mi + 4 * g + rr) * PLD + 256 + h] = f16b(acc1[rr]);
    } else {
#pragma unroll
        for (int rr = 0; rr < 4; ++rr) {
            const int i = i0 + 16 * mi + 4 * g + rr;
            const float rs = acc1[rr];
#pragma unroll
            for (int ni = 0; ni < 4; ++ni)
                outF[(size_t)i * OHF + h * COUT + 16 * ni + l15] = acc[ni][rr] / rs;
        }
    }
}

// ---------------- combine chunked f16 partials (+ optional fused classifier) ----------------
__global__ __launch_bounds__(256) void combine_kernel(const u16* __restrict__ partial,
                                                      int nchunk,
                                                      float* __restrict__ outF,
                                                      const float* __restrict__ FLw,
                                                      const float* __restrict__ FLb,
                                                      float* __restrict__ outL) {
    __shared__ float xrow[256];
    __shared__ float cred[40][4];
    const int i = blockIdx.x, c = threadIdx.x, h = c >> 6;
    float v = 0.f, rs = 0.f;
    for (int ch = 0; ch < nchunk; ++ch) {
        const u16* pc = partial + (size_t)ch * MROWS * PLD + (size_t)i * PLD;
        v += f16f(pc[c]);
        rs += f16f(pc[256 + h]);
    }
    const float r = v / rs;
    outF[(size_t)i * OHF + c] = r;
    if (!FLw) return;
    xrow[c] = r;
    __syncthreads();
    if (c < 160) {
        const int k = c >> 2, seg = c & 3;
        const float* xp = &xrow[seg * 64];
        const float* wp = &FLw[(size_t)k * OHF + seg * 64];
        float a = 0.f;
#pragma unroll
        for (int t = 0; t < 64; t += 4) {
            const float4 x4 = *(const float4*)&xp[t];
            const float4 w4 = *(const float4*)&wp[t];
            a += x4.x * w4.x + x4.y * w4.y + x4.z * w4.z + x4.w * w4.w;
        }
        cred[k][seg] = a;
    }
    __syncthreads();
    if (c < NCLS)
        outL[(size_t)i * NCLS + c] = cred[c][0] + cred[c][1] + cred[c][2] + cred[c][3] + FLb[c];
}

extern "C" void kernel_launch(void* const* d_in, const int* in_sizes, int n_in,
                              void* d_out, int out_size, void* d_ws, size_t ws_size,
                              hipStream_t stream) {
    const float* hIn = (const float*)d_in[0];
    const int*   A   = (const int*)d_in[1];
    const float* W1w = (const float*)d_in[2];
    const float* W1b = (const float*)d_in[3];
    const float* a1  = (const float*)d_in[4];
    const float* W3w = (const float*)d_in[5];
    const float* W3b = (const float*)d_in[6];
    const float* W2w = (const float*)d_in[7];
    const float* W2b = (const float*)d_in[8];
    const float* a2  = (const float*)d_in[9];
    const float* FLw = (const float*)d_in[10];
    const float* FLb = (const float*)d_in[11];
    float* outX = (float*)d_out;                     // x: (4096 x 256) fp32
    float* outL = outX + (size_t)MROWS * OHF;        // logits: (4096 x 40) fp32

    char* p = (char*)d_ws;
    auto alloc = [&](size_t bytes) { char* q = p; p += (bytes + 255) & ~(size_t)255; return q; };
    u32*   AbitsT = (u32*)alloc((size_t)MROWS * 128 * 4);
    u16*   WhF1  = (u16*)alloc((size_t)OHF * MROWS * 2);
    u16*   WhF2  = (u16*)alloc((size_t)OHF * MROWS * 2);
    float* x1f   = (float*)alloc((size_t)MROWS * OHF * 4);
    float* Cwf   = (float*)alloc((size_t)256 * 256 * 4);
    float* cbf   = (float*)alloc(256 * 4);
    float* va1   = (float*)alloc((size_t)8 * 512 * 4);
    float* vc1   = (float*)alloc(8 * 4);
    float* va2   = (float*)alloc((size_t)8 * 256 * 4);
    float* vc2   = (float*)alloc(8 * 4);
    float* srcT1 = (float*)alloc((size_t)NHEADS * MROWS * 4);
    float* dstT1 = (float*)alloc((size_t)NHEADS * MROWS * 4);
    float* srcT2 = (float*)alloc((size_t)NHEADS * MROWS * 4);
    float* dstT2 = (float*)alloc((size_t)NHEADS * MROWS * 4);
    u32*   dmu   = (u32*)alloc(8 * 4);               // [0..3]=layer1, [4..7]=layer2
    size_t fixed = (size_t)(p - (char*)d_ws);
    int nchunk = 8;
    if (fixed + (size_t)8 * MROWS * PLD * 2 > ws_size) nchunk = 4;
    u16* partial = (u16*)p;

    dim3 blk(256);
    init_kernel<<<dim3(2308), blk, 0, stream>>>(A, AbitsT, W1w, W1b, a1, W2w, W2b,
                                                W3w, W3b, a2, Cwf, cbf, va1, vc1,
                                                va2, vc2, dmu);

    auto launch_attn = [&](const u16* WhF, const float* srcT, const float* dstT,
                           const u32* dm) {
        if (nchunk == 8)
            attn_kernel<8><<<dim3(128, 8), dim3(512), 0, stream>>>(WhF, srcT, dstT, AbitsT, dm, partial, nullptr);
        else
            attn_kernel<16><<<dim3(128, 4), dim3(512), 0, stream>>>(WhF, srcT, dstT, AbitsT, dm, partial, nullptr);
    };

    // ---- layer 1 ----
    proj_kernel<<<dim3(512), blk, 0, stream>>>(hIn, W1w, W1b, 512, WhF1,
                                               va1, vc1, srcT1, dstT1, dmu);
    launch_attn(WhF1, srcT1, dstT1, dmu);
    combine_kernel<<<dim3(4096), blk, 0, stream>>>(partial, nchunk, x1f,
                                                   nullptr, nullptr, nullptr);

    // ---- layer 2 (W3∘W2 fused into Cwf; scores exact from x1f via va2) ----
    proj_kernel<<<dim3(512), blk, 0, stream>>>(x1f, Cwf, cbf, 256, WhF2,
                                               va2, vc2, srcT2, dstT2, dmu + 4);
    launch_attn(WhF2, srcT2, dstT2, dmu + 4);
    combine_kernel<<<dim3(4096), blk, 0, stream>>>(partial, nchunk, outX,
                                                   FLw, FLb, outL);
}